// Round 5
// baseline (358.300 us; speedup 1.0000x reference)
//
#include <hip/hip_runtime.h>

// Problem constants (from reference)
#define N_CELL 60000
#define N_GENE 4000
#define DIM    128
#define EPS_BN 1e-5f
#define NSLICE 8            // dst-space slices, aligned to 8 XCDs via blockIdx%8
#define SLICE_W (N_CELL / NSLICE)   // 7500
#define NB_GEMM ((N_CELL + 127) / 128)   // 469 main-GEMM blocks

// Workspace layout (4-byte units).  Zeroed region = first WS_ZERO words.
//   stats    [512]          @ 0          (sum,sumsq,mu,istd — 128 each)
//   row_ptr  [N_CELL+1]     @ 512        (int)
//   cursor   [N_CELL]       @ 60513      (int)
//   --- end of zeroed region (120513 words) ---
//   msg      [N_CELL*DIM]   @ 120576
//   ygene    [N_GENE*DIM]   @ 7800576
//   csr_src  [E]            @ 8312576    (int)
//   bsums    [256]          @ 9812576    (int)
//   Wb       [16384 bf16]   @ 9812832    (fragment-ordered bf16 Wr, 32 KB)
//   partials [NB_GEMM*256]  @ 9821024    (per-block BN sum/sumsq)
// total ~9.94M words = 39.8 MB
#define WS_STATS   0
#define WS_ROWPTR  512
#define WS_CURSOR  60513
#define WS_ZERO    120513
#define WS_MSG     120576
#define WS_YGENE   7800576
#define WS_CSR     8312576
#define WS_BSUMS   9812576
#define WS_WB      9812832
#define WS_PART    9821024

typedef __bf16 bf16x8 __attribute__((ext_vector_type(8)));
typedef float  f32x4  __attribute__((ext_vector_type(4)));

// ---------------------------------------------------------------------------
// Kernel 1: y_gene = x_gene @ Wl (fp32 — small, keeps aggregate path exact)
// ---------------------------------------------------------------------------
__global__ __launch_bounds__(128) void ygene_gemm(
    const float* __restrict__ xg, const float* __restrict__ Wl,
    float* __restrict__ y) {
  const int j  = threadIdx.x;
  const int r0 = blockIdx.x * 8;
  float acc[8] = {};
  for (int k = 0; k < DIM; ++k) {
    const float w = Wl[k * DIM + j];
#pragma unroll
    for (int r = 0; r < 8; ++r)
      acc[r] += xg[(size_t)(r0 + r) * DIM + k] * w;
  }
#pragma unroll
  for (int r = 0; r < 8; ++r)
    y[(size_t)(r0 + r) * DIM + j] = acc[r];
}

// ---------------------------------------------------------------------------
// conv_w: Wr fp32 [128k][128j] -> fragment-ordered bf16 for 16x16x32 MFMA.
// ---------------------------------------------------------------------------
__global__ __launch_bounds__(256) void conv_w(
    const float* __restrict__ w, unsigned short* __restrict__ wb) {
  const int i = blockIdx.x * 256 + threadIdx.x;  // 0..16383
  const int k = i >> 7, j = i & 127;
  const int chunk = (k >> 5) * 8 + (j >> 4);
  const int lane  = ((k >> 3) & 3) * 16 + (j & 15);
  const int e     = k & 7;
  const __bf16 b  = (__bf16)w[i];
  wb[(chunk * 64 + lane) * 8 + e] = __builtin_bit_cast(unsigned short, b);
}

// ---------------------------------------------------------------------------
// CSR build step 1: histogram of dst into row_ptr[1+d]
// ---------------------------------------------------------------------------
__global__ __launch_bounds__(256) void hist_dst(
    const int* __restrict__ dst, int* __restrict__ rp1, int E) {
  const int step = gridDim.x * blockDim.x;
  for (int i = blockIdx.x * blockDim.x + threadIdx.x; i < E; i += step)
    atomicAdd(&rp1[dst[i]], 1);
}

__global__ __launch_bounds__(256) void scan1(
    int* __restrict__ rp1, int* __restrict__ bsums, int n) {
  __shared__ int s[256];
  const int t = threadIdx.x;
  const int i = blockIdx.x * 256 + t;
  int v = (i < n) ? rp1[i] : 0;
  s[t] = v;
  __syncthreads();
#pragma unroll
  for (int off = 1; off < 256; off <<= 1) {
    int x = (t >= off) ? s[t - off] : 0;
    __syncthreads();
    s[t] += x;
    __syncthreads();
  }
  if (i < n) rp1[i] = s[t];
  if (t == 255) bsums[blockIdx.x] = s[255];
}

__global__ __launch_bounds__(256) void scan2(int* __restrict__ bsums, int nb) {
  __shared__ int s[256];
  const int t = threadIdx.x;
  int v = (t < nb) ? bsums[t] : 0;
  s[t] = v;
  __syncthreads();
#pragma unroll
  for (int off = 1; off < 256; off <<= 1) {
    int x = (t >= off) ? s[t - off] : 0;
    __syncthreads();
    s[t] += x;
    __syncthreads();
  }
  if (t < nb) bsums[t] = s[t] - v;  // exclusive
}

__global__ __launch_bounds__(256) void scan3(
    int* __restrict__ rp1, const int* __restrict__ bsums, int n) {
  const int i = blockIdx.x * 256 + threadIdx.x;
  if (i < n) rp1[i] += bsums[blockIdx.x];
}

// ---------------------------------------------------------------------------
// CSR build step 3: fill csr_src, XCD-sliced (see R3 notes)
// ---------------------------------------------------------------------------
__global__ __launch_bounds__(256) void csr_fill_sliced(
    const int* __restrict__ src, const int* __restrict__ dst,
    const int* __restrict__ rp, int* __restrict__ cursor,
    int* __restrict__ csr, int E) {
  const int slice = blockIdx.x & (NSLICE - 1);
  const int lo    = slice * SLICE_W;
  const int bidx  = blockIdx.x >> 3;
  const int bper  = gridDim.x >> 3;
  const int step  = bper * 256;
  for (int i = bidx * 256 + threadIdx.x; i < E; i += step) {
    const int d = dst[i];
    if ((unsigned)(d - lo) >= (unsigned)SLICE_W) continue;
    const int pos = atomicAdd(&cursor[d], 1);
    csr[rp[d] + pos] = src[i];
  }
}

// ---------------------------------------------------------------------------
// gather-aggregate, half-wave float4: lanes 0-31 take even edges, 32-63 odd.
// Each lane loads 16 B per edge (vs 8 B before); 2-deep unroll keeps 2
// independent row gathers in flight per half.  Cross-half combine via
// __shfl_down(.,32) once per cell.
// ---------------------------------------------------------------------------
__global__ __launch_bounds__(256) void aggregate(
    const int* __restrict__ rp, const int* __restrict__ csr,
    const float* __restrict__ y, float* __restrict__ msg) {
  const int wave = (blockIdx.x * 256 + threadIdx.x) >> 6;
  const int lane = threadIdx.x & 63;
  if (wave >= N_CELL) return;
  const int half = lane >> 5;     // which edge of the pair
  const int sub  = lane & 31;     // 4-float dim group
  const int beg = rp[wave], end = rp[wave + 1];
  const int deg = end - beg;

  f32x4 a0 = {0.f, 0.f, 0.f, 0.f}, a1 = {0.f, 0.f, 0.f, 0.f};
  int e = beg;
  for (; e + 3 < end; e += 4) {            // 4 edges: 2 per half, independent
    const int s0 = csr[e + half];
    const int s1 = csr[e + 2 + half];
    const f32x4 v0 = *(const f32x4*)(y + (size_t)s0 * DIM + sub * 4);
    const f32x4 v1 = *(const f32x4*)(y + (size_t)s1 * DIM + sub * 4);
    a0 += v0;
    a1 += v1;
  }
  if (e + 1 < end) {                       // 2 edges
    const int s = csr[e + half];
    a0 += *(const f32x4*)(y + (size_t)s * DIM + sub * 4);
    e += 2;
  }
  if (e < end && half == 0) {              // last single edge
    const int s = csr[e];
    a1 += *(const f32x4*)(y + (size_t)s * DIM + sub * 4);
  }
  f32x4 t = a0 + a1;
  t.x += __shfl_down(t.x, 32);
  t.y += __shfl_down(t.y, 32);
  t.z += __shfl_down(t.z, 32);
  t.w += __shfl_down(t.w, 32);
  if (half == 0) {
    const float ic = 1.0f / fmaxf((float)deg, 1.0f);
    *(f32x4*)(msg + (size_t)wave * DIM + sub * 4) = t * ic;
  }
}

// ---------------------------------------------------------------------------
// main GEMM on matrix cores: out_pre = bf16(x_cell) @ bf16(Wr) + msg + bl,
// with fused BN partial sums (per-block, deterministic).
// ---------------------------------------------------------------------------
__global__ __launch_bounds__(256) void main_gemm_mfma(
    const float* __restrict__ xc, const unsigned short* __restrict__ wb,
    const float* __restrict__ bl, const float* __restrict__ msg,
    float* __restrict__ out, float* __restrict__ partials) {
  __shared__ unsigned short a_lds[128 * 128];  // 32 KB
  __shared__ float ps[4][64], ps2[4][64];      // per-wave BN partials, 2 KB
  const int t    = threadIdx.x;
  const int row0 = blockIdx.x * 128;

  // ---- stage A: fp32 -> bf16, swizzled ----
  {
    const int row  = t >> 1;
    const int h    = t & 1;
    const int grow = row0 + row;
    const bool ok  = grow < N_CELL;
    const float* xrow = xc + (size_t)grow * DIM;
#pragma unroll
    for (int i = 0; i < 4; ++i) {
      const int kk = h * 64 + i * 16;
      float4 f0, f1, f2, f3;
      if (ok) {
        f0 = *(const float4*)(xrow + kk);
        f1 = *(const float4*)(xrow + kk + 4);
        f2 = *(const float4*)(xrow + kk + 8);
        f3 = *(const float4*)(xrow + kk + 12);
      } else {
        f0 = f1 = f2 = f3 = make_float4(0.f, 0.f, 0.f, 0.f);
      }
      const float fv[16] = {f0.x, f0.y, f0.z, f0.w, f1.x, f1.y, f1.z, f1.w,
                            f2.x, f2.y, f2.z, f2.w, f3.x, f3.y, f3.z, f3.w};
      union { unsigned short u[16]; uint4 q[2]; } pk;
#pragma unroll
      for (int e = 0; e < 16; ++e) {
        const __bf16 b = (__bf16)fv[e];
        pk.u[e] = __builtin_bit_cast(unsigned short, b);
      }
      const int s0 = ((kk >> 3) + 0) ^ (row & 15);
      const int s1 = ((kk >> 3) + 1) ^ (row & 15);
      *(uint4*)&a_lds[row * 128 + s0 * 8] = pk.q[0];
      *(uint4*)&a_lds[row * 128 + s1 * 8] = pk.q[1];
    }
  }
  __syncthreads();

  const int w   = t >> 6, l = t & 63;
  const int wr  = w >> 1, wc = w & 1;
  const int l15 = l & 15, lq = l >> 4;

  f32x4 acc[4][4];
#pragma unroll
  for (int g = 0; g < 4; ++g)
#pragma unroll
    for (int c = 0; c < 4; ++c) acc[g][c] = (f32x4){0.f, 0.f, 0.f, 0.f};

#pragma unroll
  for (int ks = 0; ks < 4; ++ks) {
    bf16x8 bfr[4];
#pragma unroll
    for (int c = 0; c < 4; ++c)
      bfr[c] = *(const bf16x8*)(wb +
                (size_t)(((ks * 8 + wc * 4 + c) * 64 + l) * 8));
    bf16x8 afr[4];
#pragma unroll
    for (int g = 0; g < 4; ++g) {
      const int row = wr * 64 + g * 16 + l15;   // row & 15 == l15
      const int s   = (ks * 4 + lq) ^ l15;
      afr[g] = *(const bf16x8*)&a_lds[row * 128 + s * 8];
    }
#pragma unroll
    for (int g = 0; g < 4; ++g)
#pragma unroll
      for (int c = 0; c < 4; ++c)
        acc[g][c] = __builtin_amdgcn_mfma_f32_16x16x32_bf16(
            afr[g], bfr[c], acc[g][c], 0, 0, 0);
  }

  // epilogue: + msg + bias, with per-column sum/sumsq accumulation
  float csum[4] = {0.f, 0.f, 0.f, 0.f}, csq[4] = {0.f, 0.f, 0.f, 0.f};
#pragma unroll
  for (int g = 0; g < 4; ++g) {
#pragma unroll
    for (int c = 0; c < 4; ++c) {
      const int col = wc * 64 + c * 16 + l15;
      const float b = bl[col];
#pragma unroll
      for (int r = 0; r < 4; ++r) {
        const int grow = row0 + wr * 64 + g * 16 + lq * 4 + r;
        if (grow < N_CELL) {
          const float val =
              acc[g][c][r] + msg[(size_t)grow * DIM + col] + b;
          out[(size_t)grow * DIM + col] = val;
          csum[c] += val;
          csq[c]  += val * val;
        }
      }
    }
  }
  // reduce the 4 lanes (lq=0..3) that share each column
#pragma unroll
  for (int c = 0; c < 4; ++c) {
    csum[c] += __shfl_xor(csum[c], 16);
    csum[c] += __shfl_xor(csum[c], 32);
    csq[c]  += __shfl_xor(csq[c], 16);
    csq[c]  += __shfl_xor(csq[c], 32);
  }
  if (lq == 0) {
#pragma unroll
    for (int c = 0; c < 4; ++c) {
      ps[w][c * 16 + l15]  = csum[c];
      ps2[w][c * 16 + l15] = csq[c];
    }
  }
  __syncthreads();
  {
    const int which = t >> 7;          // 0: sum, 1: sumsq
    const int col   = t & 127;
    const int wcc   = col >> 6;        // waves wcc and 2+wcc share this col
    const int idx   = col & 63;
    const float v = which ? (ps2[wcc][idx] + ps2[2 + wcc][idx])
                          : (ps[wcc][idx] + ps[2 + wcc][idx]);
    partials[(size_t)blockIdx.x * 256 + t] = v;
  }
}

// ---------------------------------------------------------------------------
// bn_reduce: fold per-block partials -> mu / inv_std (deterministic order)
// ---------------------------------------------------------------------------
__global__ __launch_bounds__(256) void bn_reduce(
    const float* __restrict__ partials, float* __restrict__ stats, int nb) {
  const int t = threadIdx.x;
  float s = 0.f;
  for (int b = 0; b < nb; ++b) s += partials[(size_t)b * 256 + t];
  __shared__ float sh[256];
  sh[t] = s;
  __syncthreads();
  if (t < 128) {
    const float mu  = sh[t] / (float)N_CELL;
    const float var = sh[128 + t] / (float)N_CELL - mu * mu;
    stats[256 + t] = mu;
    stats[384 + t] = rsqrtf(var + EPS_BN);
  }
}

// ---------------------------------------------------------------------------
// bn_apply: normalize in place (float4)
// ---------------------------------------------------------------------------
__global__ __launch_bounds__(256) void bn_apply(
    float* __restrict__ out, const float* __restrict__ stats) {
  const size_t total = (size_t)N_CELL * DIM / 4;
  const size_t step  = (size_t)gridDim.x * blockDim.x;
  for (size_t i = (size_t)blockIdx.x * blockDim.x + threadIdx.x; i < total;
       i += step) {
    float4 v = ((float4*)out)[i];
    const int col = (int)((i * 4) & (DIM - 1));
    v.x = (v.x - stats[256 + col + 0]) * stats[384 + col + 0];
    v.y = (v.y - stats[256 + col + 1]) * stats[384 + col + 1];
    v.z = (v.z - stats[256 + col + 2]) * stats[384 + col + 2];
    v.w = (v.w - stats[256 + col + 3]) * stats[384 + col + 3];
    ((float4*)out)[i] = v;
  }
}

// ---------------------------------------------------------------------------
extern "C" void kernel_launch(void* const* d_in, const int* in_sizes, int n_in,
                              void* d_out, int out_size, void* d_ws,
                              size_t ws_size, hipStream_t stream) {
  const float* x_cell = (const float*)d_in[0];
  const float* x_gene = (const float*)d_in[1];
  const float* Wl_gc  = (const float*)d_in[2];
  const float* bl_gc  = (const float*)d_in[3];
  const float* Wr_gc  = (const float*)d_in[4];
  // d_in[5..7] (cg weights) are dead: the gene branch never feeds the output.
  const int* gc_src = (const int*)d_in[8];
  const int* gc_dst = (const int*)d_in[9];
  const int  E      = in_sizes[8];

  const float* Wl1 = Wl_gc + DIM * DIM;   // layer 1 (last)
  const float* bl1 = bl_gc + DIM;
  const float* Wr1 = Wr_gc + DIM * DIM;

  float* ws    = (float*)d_ws;
  float* stats = ws + WS_STATS;
  int*   rp    = (int*)(ws + WS_ROWPTR);
  int*   cur   = (int*)(ws + WS_CURSOR);
  float* msg   = ws + WS_MSG;
  float* ygene = ws + WS_YGENE;
  int*   csr   = (int*)(ws + WS_CSR);
  int*   bsums = (int*)(ws + WS_BSUMS);
  unsigned short* Wb = (unsigned short*)(ws + WS_WB);
  float* part  = ws + WS_PART;
  float* out   = (float*)d_out;

  hipMemsetAsync(d_ws, 0, (size_t)WS_ZERO * sizeof(float), stream);

  conv_w<<<64, 256, 0, stream>>>(Wr1, Wb);
  ygene_gemm<<<N_GENE / 8, 128, 0, stream>>>(x_gene, Wl1, ygene);

  const int NB = (N_CELL + 255) / 256;
  hist_dst<<<2048, 256, 0, stream>>>(gc_dst, rp + 1, E);
  scan1<<<NB, 256, 0, stream>>>(rp + 1, bsums, N_CELL);
  scan2<<<1, 256, 0, stream>>>(bsums, NB);
  scan3<<<NB, 256, 0, stream>>>(rp + 1, bsums, N_CELL);
  csr_fill_sliced<<<2048, 256, 0, stream>>>(gc_src, gc_dst, rp, cur, csr, E);

  aggregate<<<(N_CELL + 3) / 4, 256, 0, stream>>>(rp, csr, ygene, msg);
  main_gemm_mfma<<<NB_GEMM, 256, 0, stream>>>(x_cell, Wb, bl1, msg, out, part);

  bn_reduce<<<1, 256, 0, stream>>>(part, stats, NB_GEMM);
  bn_apply<<<2048, 256, 0, stream>>>(out, stats);
}

// Round 6
// 255.672 us; speedup vs baseline: 1.4014x; 1.4014x over previous
//
#include <hip/hip_runtime.h>

// Problem constants (from reference)
#define N_CELL 60000
#define N_GENE 4000
#define DIM    128
#define EPS_BN 1e-5f
#define NSLICE 8            // dst-space slices, aligned to 8 XCDs via blockIdx%8
#define SLICE_W (N_CELL / NSLICE)   // 7500
#define NB_GEMM ((N_CELL + 127) / 128)   // 469 main-GEMM blocks

// Workspace layout (4-byte units).  Zeroed region = first WS_ZERO words.
//   stats    [512]          @ 0          (sum,sumsq,mu,istd — 128 each)
//   row_ptr  [N_CELL+1]     @ 512        (int)
//   cursor   [N_CELL]       @ 60513      (int)
//   --- end of zeroed region (120513 words) ---
//   msg      [N_CELL*DIM]   @ 120576
//   ygene    [N_GENE*DIM]   @ 7800576
//   csr_src  [E]            @ 8312576    (int)
//   bsums    [256]          @ 9812576    (int)
//   Wb       [16384 bf16]   @ 9812832    (fragment-ordered bf16 Wr, 32 KB)
// total ~9.82M words = 39.3 MB
#define WS_STATS   0
#define WS_ROWPTR  512
#define WS_CURSOR  60513
#define WS_ZERO    120513
#define WS_MSG     120576
#define WS_YGENE   7800576
#define WS_CSR     8312576
#define WS_BSUMS   9812576
#define WS_WB      9812832

typedef __bf16 bf16x8 __attribute__((ext_vector_type(8)));
typedef float  f32x4  __attribute__((ext_vector_type(4)));

// ---------------------------------------------------------------------------
// Kernel 1: y_gene = x_gene @ Wl (fp32 — small, keeps aggregate path exact)
// ---------------------------------------------------------------------------
__global__ __launch_bounds__(128) void ygene_gemm(
    const float* __restrict__ xg, const float* __restrict__ Wl,
    float* __restrict__ y) {
  const int j  = threadIdx.x;
  const int r0 = blockIdx.x * 8;
  float acc[8] = {};
  for (int k = 0; k < DIM; ++k) {
    const float w = Wl[k * DIM + j];
#pragma unroll
    for (int r = 0; r < 8; ++r)
      acc[r] += xg[(size_t)(r0 + r) * DIM + k] * w;
  }
#pragma unroll
  for (int r = 0; r < 8; ++r)
    y[(size_t)(r0 + r) * DIM + j] = acc[r];
}

// ---------------------------------------------------------------------------
// conv_w: Wr fp32 [128k][128j] -> fragment-ordered bf16 for 16x16x32 MFMA.
// ---------------------------------------------------------------------------
__global__ __launch_bounds__(256) void conv_w(
    const float* __restrict__ w, unsigned short* __restrict__ wb) {
  const int i = blockIdx.x * 256 + threadIdx.x;  // 0..16383
  const int k = i >> 7, j = i & 127;
  const int chunk = (k >> 5) * 8 + (j >> 4);
  const int lane  = ((k >> 3) & 3) * 16 + (j & 15);
  const int e     = k & 7;
  const __bf16 b  = (__bf16)w[i];
  wb[(chunk * 64 + lane) * 8 + e] = __builtin_bit_cast(unsigned short, b);
}

// ---------------------------------------------------------------------------
// CSR build step 1: histogram of dst into row_ptr[1+d]
// ---------------------------------------------------------------------------
__global__ __launch_bounds__(256) void hist_dst(
    const int* __restrict__ dst, int* __restrict__ rp1, int E) {
  const int step = gridDim.x * blockDim.x;
  for (int i = blockIdx.x * blockDim.x + threadIdx.x; i < E; i += step)
    atomicAdd(&rp1[dst[i]], 1);
}

__global__ __launch_bounds__(256) void scan1(
    int* __restrict__ rp1, int* __restrict__ bsums, int n) {
  __shared__ int s[256];
  const int t = threadIdx.x;
  const int i = blockIdx.x * 256 + t;
  int v = (i < n) ? rp1[i] : 0;
  s[t] = v;
  __syncthreads();
#pragma unroll
  for (int off = 1; off < 256; off <<= 1) {
    int x = (t >= off) ? s[t - off] : 0;
    __syncthreads();
    s[t] += x;
    __syncthreads();
  }
  if (i < n) rp1[i] = s[t];
  if (t == 255) bsums[blockIdx.x] = s[255];
}

__global__ __launch_bounds__(256) void scan2(int* __restrict__ bsums, int nb) {
  __shared__ int s[256];
  const int t = threadIdx.x;
  int v = (t < nb) ? bsums[t] : 0;
  s[t] = v;
  __syncthreads();
#pragma unroll
  for (int off = 1; off < 256; off <<= 1) {
    int x = (t >= off) ? s[t - off] : 0;
    __syncthreads();
    s[t] += x;
    __syncthreads();
  }
  if (t < nb) bsums[t] = s[t] - v;  // exclusive
}

__global__ __launch_bounds__(256) void scan3(
    int* __restrict__ rp1, const int* __restrict__ bsums, int n) {
  const int i = blockIdx.x * 256 + threadIdx.x;
  if (i < n) rp1[i] += bsums[blockIdx.x];
}

// ---------------------------------------------------------------------------
// CSR build step 3: fill csr_src, XCD-sliced (see R3 notes)
// ---------------------------------------------------------------------------
__global__ __launch_bounds__(256) void csr_fill_sliced(
    const int* __restrict__ src, const int* __restrict__ dst,
    const int* __restrict__ rp, int* __restrict__ cursor,
    int* __restrict__ csr, int E) {
  const int slice = blockIdx.x & (NSLICE - 1);
  const int lo    = slice * SLICE_W;
  const int bidx  = blockIdx.x >> 3;
  const int bper  = gridDim.x >> 3;
  const int step  = bper * 256;
  for (int i = bidx * 256 + threadIdx.x; i < E; i += step) {
    const int d = dst[i];
    if ((unsigned)(d - lo) >= (unsigned)SLICE_W) continue;
    const int pos = atomicAdd(&cursor[d], 1);
    csr[rp[d] + pos] = src[i];
  }
}

// ---------------------------------------------------------------------------
// gather-aggregate, half-wave float4: lanes 0-31 take even edges, 32-63 odd.
// ---------------------------------------------------------------------------
__global__ __launch_bounds__(256) void aggregate(
    const int* __restrict__ rp, const int* __restrict__ csr,
    const float* __restrict__ y, float* __restrict__ msg) {
  const int wave = (blockIdx.x * 256 + threadIdx.x) >> 6;
  const int lane = threadIdx.x & 63;
  if (wave >= N_CELL) return;
  const int half = lane >> 5;     // which edge of the pair
  const int sub  = lane & 31;     // 4-float dim group
  const int beg = rp[wave], end = rp[wave + 1];
  const int deg = end - beg;

  f32x4 a0 = {0.f, 0.f, 0.f, 0.f}, a1 = {0.f, 0.f, 0.f, 0.f};
  int e = beg;
  for (; e + 3 < end; e += 4) {            // 4 edges: 2 per half, independent
    const int s0 = csr[e + half];
    const int s1 = csr[e + 2 + half];
    const f32x4 v0 = *(const f32x4*)(y + (size_t)s0 * DIM + sub * 4);
    const f32x4 v1 = *(const f32x4*)(y + (size_t)s1 * DIM + sub * 4);
    a0 += v0;
    a1 += v1;
  }
  if (e + 1 < end) {                       // 2 edges
    const int s = csr[e + half];
    a0 += *(const f32x4*)(y + (size_t)s * DIM + sub * 4);
    e += 2;
  }
  if (e < end && half == 0) {              // last single edge
    const int s = csr[e];
    a1 += *(const f32x4*)(y + (size_t)s * DIM + sub * 4);
  }
  f32x4 t = a0 + a1;
  t.x += __shfl_down(t.x, 32);
  t.y += __shfl_down(t.y, 32);
  t.z += __shfl_down(t.z, 32);
  t.w += __shfl_down(t.w, 32);
  if (half == 0) {
    const float ic = 1.0f / fmaxf((float)deg, 1.0f);
    *(f32x4*)(msg + (size_t)wave * DIM + sub * 4) = t * ic;
  }
}

// ---------------------------------------------------------------------------
// main GEMM on matrix cores: out_pre = bf16(x_cell) @ bf16(Wr) + msg + bl,
// fused BN partial sums -> ONE atomicAdd per thread into stats[0:256]
// (469 blocks x 256 lanes over 256 addresses: negligible contention; the
// single-block serial bn_reduce this replaces was 114 us of pure latency).
// ---------------------------------------------------------------------------
__global__ __launch_bounds__(256) void main_gemm_mfma(
    const float* __restrict__ xc, const unsigned short* __restrict__ wb,
    const float* __restrict__ bl, const float* __restrict__ msg,
    float* __restrict__ out, float* __restrict__ stats) {
  __shared__ unsigned short a_lds[128 * 128];  // 32 KB
  __shared__ float ps[4][64], ps2[4][64];      // per-wave BN partials, 2 KB
  const int t    = threadIdx.x;
  const int row0 = blockIdx.x * 128;

  // ---- stage A: fp32 -> bf16, swizzled ----
  {
    const int row  = t >> 1;
    const int h    = t & 1;
    const int grow = row0 + row;
    const bool ok  = grow < N_CELL;
    const float* xrow = xc + (size_t)grow * DIM;
#pragma unroll
    for (int i = 0; i < 4; ++i) {
      const int kk = h * 64 + i * 16;
      float4 f0, f1, f2, f3;
      if (ok) {
        f0 = *(const float4*)(xrow + kk);
        f1 = *(const float4*)(xrow + kk + 4);
        f2 = *(const float4*)(xrow + kk + 8);
        f3 = *(const float4*)(xrow + kk + 12);
      } else {
        f0 = f1 = f2 = f3 = make_float4(0.f, 0.f, 0.f, 0.f);
      }
      const float fv[16] = {f0.x, f0.y, f0.z, f0.w, f1.x, f1.y, f1.z, f1.w,
                            f2.x, f2.y, f2.z, f2.w, f3.x, f3.y, f3.z, f3.w};
      union { unsigned short u[16]; uint4 q[2]; } pk;
#pragma unroll
      for (int e = 0; e < 16; ++e) {
        const __bf16 b = (__bf16)fv[e];
        pk.u[e] = __builtin_bit_cast(unsigned short, b);
      }
      const int s0 = ((kk >> 3) + 0) ^ (row & 15);
      const int s1 = ((kk >> 3) + 1) ^ (row & 15);
      *(uint4*)&a_lds[row * 128 + s0 * 8] = pk.q[0];
      *(uint4*)&a_lds[row * 128 + s1 * 8] = pk.q[1];
    }
  }
  __syncthreads();

  const int w   = t >> 6, l = t & 63;
  const int wr  = w >> 1, wc = w & 1;
  const int l15 = l & 15, lq = l >> 4;

  f32x4 acc[4][4];
#pragma unroll
  for (int g = 0; g < 4; ++g)
#pragma unroll
    for (int c = 0; c < 4; ++c) acc[g][c] = (f32x4){0.f, 0.f, 0.f, 0.f};

#pragma unroll
  for (int ks = 0; ks < 4; ++ks) {
    bf16x8 bfr[4];
#pragma unroll
    for (int c = 0; c < 4; ++c)
      bfr[c] = *(const bf16x8*)(wb +
                (size_t)(((ks * 8 + wc * 4 + c) * 64 + l) * 8));
    bf16x8 afr[4];
#pragma unroll
    for (int g = 0; g < 4; ++g) {
      const int row = wr * 64 + g * 16 + l15;   // row & 15 == l15
      const int s   = (ks * 4 + lq) ^ l15;
      afr[g] = *(const bf16x8*)&a_lds[row * 128 + s * 8];
    }
#pragma unroll
    for (int g = 0; g < 4; ++g)
#pragma unroll
      for (int c = 0; c < 4; ++c)
        acc[g][c] = __builtin_amdgcn_mfma_f32_16x16x32_bf16(
            afr[g], bfr[c], acc[g][c], 0, 0, 0);
  }

  // epilogue: + msg + bias, with per-column sum/sumsq accumulation
  float csum[4] = {0.f, 0.f, 0.f, 0.f}, csq[4] = {0.f, 0.f, 0.f, 0.f};
#pragma unroll
  for (int g = 0; g < 4; ++g) {
#pragma unroll
    for (int c = 0; c < 4; ++c) {
      const int col = wc * 64 + c * 16 + l15;
      const float b = bl[col];
#pragma unroll
      for (int r = 0; r < 4; ++r) {
        const int grow = row0 + wr * 64 + g * 16 + lq * 4 + r;
        if (grow < N_CELL) {
          const float val =
              acc[g][c][r] + msg[(size_t)grow * DIM + col] + b;
          out[(size_t)grow * DIM + col] = val;
          csum[c] += val;
          csq[c]  += val * val;
        }
      }
    }
  }
  // reduce the 4 lanes (lq=0..3) that share each column
#pragma unroll
  for (int c = 0; c < 4; ++c) {
    csum[c] += __shfl_xor(csum[c], 16);
    csum[c] += __shfl_xor(csum[c], 32);
    csq[c]  += __shfl_xor(csq[c], 16);
    csq[c]  += __shfl_xor(csq[c], 32);
  }
  if (lq == 0) {
#pragma unroll
    for (int c = 0; c < 4; ++c) {
      ps[w][c * 16 + l15]  = csum[c];
      ps2[w][c * 16 + l15] = csq[c];
    }
  }
  __syncthreads();
  {
    const int which = t >> 7;          // 0: sum, 1: sumsq
    const int col   = t & 127;
    const int wcc   = col >> 6;        // waves wcc and 2+wcc share this col
    const int idx   = col & 63;
    const float v = which ? (ps2[wcc][idx] + ps2[2 + wcc][idx])
                          : (ps[wcc][idx] + ps[2 + wcc][idx]);
    unsafeAtomicAdd(&stats[t], v);     // t in [0,256): sum[128] | sumsq[128]
  }
}

// ---------------------------------------------------------------------------
// bn_finalize: mu / inv_std from accumulated sums (1 block, ~2 us)
// ---------------------------------------------------------------------------
__global__ __launch_bounds__(128) void bn_finalize(float* __restrict__ stats) {
  const int j = threadIdx.x;
  const float mu  = stats[j] / (float)N_CELL;
  const float var = stats[128 + j] / (float)N_CELL - mu * mu;
  stats[256 + j] = mu;
  stats[384 + j] = rsqrtf(var + EPS_BN);
}

// ---------------------------------------------------------------------------
// bn_apply: normalize in place (float4)
// ---------------------------------------------------------------------------
__global__ __launch_bounds__(256) void bn_apply(
    float* __restrict__ out, const float* __restrict__ stats) {
  const size_t total = (size_t)N_CELL * DIM / 4;
  const size_t step  = (size_t)gridDim.x * blockDim.x;
  for (size_t i = (size_t)blockIdx.x * blockDim.x + threadIdx.x; i < total;
       i += step) {
    float4 v = ((float4*)out)[i];
    const int col = (int)((i * 4) & (DIM - 1));
    v.x = (v.x - stats[256 + col + 0]) * stats[384 + col + 0];
    v.y = (v.y - stats[256 + col + 1]) * stats[384 + col + 1];
    v.z = (v.z - stats[256 + col + 2]) * stats[384 + col + 2];
    v.w = (v.w - stats[256 + col + 3]) * stats[384 + col + 3];
    ((float4*)out)[i] = v;
  }
}

// ---------------------------------------------------------------------------
extern "C" void kernel_launch(void* const* d_in, const int* in_sizes, int n_in,
                              void* d_out, int out_size, void* d_ws,
                              size_t ws_size, hipStream_t stream) {
  const float* x_cell = (const float*)d_in[0];
  const float* x_gene = (const float*)d_in[1];
  const float* Wl_gc  = (const float*)d_in[2];
  const float* bl_gc  = (const float*)d_in[3];
  const float* Wr_gc  = (const float*)d_in[4];
  // d_in[5..7] (cg weights) are dead: the gene branch never feeds the output.
  const int* gc_src = (const int*)d_in[8];
  const int* gc_dst = (const int*)d_in[9];
  const int  E      = in_sizes[8];

  const float* Wl1 = Wl_gc + DIM * DIM;   // layer 1 (last)
  const float* bl1 = bl_gc + DIM;
  const float* Wr1 = Wr_gc + DIM * DIM;

  float* ws    = (float*)d_ws;
  float* stats = ws + WS_STATS;
  int*   rp    = (int*)(ws + WS_ROWPTR);
  int*   cur   = (int*)(ws + WS_CURSOR);
  float* msg   = ws + WS_MSG;
  float* ygene = ws + WS_YGENE;
  int*   csr   = (int*)(ws + WS_CSR);
  int*   bsums = (int*)(ws + WS_BSUMS);
  unsigned short* Wb = (unsigned short*)(ws + WS_WB);
  float* out   = (float*)d_out;

  hipMemsetAsync(d_ws, 0, (size_t)WS_ZERO * sizeof(float), stream);

  conv_w<<<64, 256, 0, stream>>>(Wr1, Wb);
  ygene_gemm<<<N_GENE / 8, 128, 0, stream>>>(x_gene, Wl1, ygene);

  const int NB = (N_CELL + 255) / 256;
  hist_dst<<<2048, 256, 0, stream>>>(gc_dst, rp + 1, E);
  scan1<<<NB, 256, 0, stream>>>(rp + 1, bsums, N_CELL);
  scan2<<<1, 256, 0, stream>>>(bsums, NB);
  scan3<<<NB, 256, 0, stream>>>(rp + 1, bsums, N_CELL);
  csr_fill_sliced<<<2048, 256, 0, stream>>>(gc_src, gc_dst, rp, cur, csr, E);

  aggregate<<<(N_CELL + 3) / 4, 256, 0, stream>>>(rp, csr, ygene, msg);
  main_gemm_mfma<<<NB_GEMM, 256, 0, stream>>>(x_cell, Wb, bl1, msg, out,
                                              stats);

  bn_finalize<<<1, 128, 0, stream>>>(stats);
  bn_apply<<<2048, 256, 0, stream>>>(out, stats);
}

// Round 8
// 137.013 us; speedup vs baseline: 2.6151x; 1.8660x over previous
//
#include <hip/hip_runtime.h>

// Problem constants (from reference)
#define N_CELL 60000
#define N_GENE 4000
#define DIM    128
#define EPS_BN 1e-5f

#define NBUCKET 469            // ceil(60000/128) buckets of 128 cells
#define CAP     3700           // per-bucket capacity: mean 3200, +8.8 sigma
#define PBLK_I4 2048           // int4s per partition block (= 8192 edges)
#define NB_GEMM ((N_CELL + 127) / 128)   // 469 main-GEMM blocks

// Workspace layout (4-byte words).  Zeroed region = first WS_ZERO words.
//   stats  [512]            @ 0        (sum,sumsq,mu,istd — 128 each)
//   gcur   [512]            @ 512      (int; per-bucket edge counters, 469 used)
//   --- end of zeroed region (1024 words) ---
//   msg    [N_CELL*DIM]     @ 1024               -> ends 7,681,024
//   ygene  [N_GENE*DIM]     @ 7,681,024          -> ends 8,193,024
//   gedges [NBUCKET*CAP]    @ 8,193,024 (u32)    -> ends 9,928,324
//   Wb     [16384 bf16]     @ 9,928,324 (8192 w) -> ends 9,936,516
// total 9,936,516 words = 39.75 MB
#define WS_STATS  0
#define WS_GCUR   512
#define WS_ZERO   1024
#define WS_MSG    1024
#define WS_YGENE  7681024
#define WS_GEDGE  8193024
#define WS_WB     9928324

typedef __bf16 bf16x8 __attribute__((ext_vector_type(8)));
typedef float  f32x4  __attribute__((ext_vector_type(4)));

// ---------------------------------------------------------------------------
// Kernel 1: y_gene = x_gene @ Wl (fp32 — small, keeps aggregate path exact)
// ---------------------------------------------------------------------------
__global__ __launch_bounds__(128) void ygene_gemm(
    const float* __restrict__ xg, const float* __restrict__ Wl,
    float* __restrict__ y) {
  const int j  = threadIdx.x;
  const int r0 = blockIdx.x * 8;
  float acc[8] = {};
  for (int k = 0; k < DIM; ++k) {
    const float w = Wl[k * DIM + j];
#pragma unroll
    for (int r = 0; r < 8; ++r)
      acc[r] += xg[(size_t)(r0 + r) * DIM + k] * w;
  }
#pragma unroll
  for (int r = 0; r < 8; ++r)
    y[(size_t)(r0 + r) * DIM + j] = acc[r];
}

// ---------------------------------------------------------------------------
// conv_w: Wr fp32 [128k][128j] -> fragment-ordered bf16 for 16x16x32 MFMA.
// ---------------------------------------------------------------------------
__global__ __launch_bounds__(256) void conv_w(
    const float* __restrict__ w, unsigned short* __restrict__ wb) {
  const int i = blockIdx.x * 256 + threadIdx.x;  // 0..16383
  const int k = i >> 7, j = i & 127;
  const int chunk = (k >> 5) * 8 + (j >> 4);
  const int lane  = ((k >> 3) & 3) * 16 + (j & 15);
  const int e     = k & 7;
  const __bf16 b  = (__bf16)w[i];
  wb[(chunk * 64 + lane) * 8 + e] = __builtin_bit_cast(unsigned short, b);
}

// ---------------------------------------------------------------------------
// partition_edges: pack (dst<<12 | src) and counting-sort 8192-edge chunks
// into 469 global bucket regions (bucket = dst>>7).  LDS-local sort makes
// the global writes contiguous runs (~17 edges = ~70 B) instead of random
// 4 B scatters -> no RFO/partial-line writeback amplification.
// R8 FIX: hist/off/cur/gbase sized 512 and FULLY zeroed — the pair-sum scan
// reads hist[0..511]; R7's hist[470] made threads t>=235 read OOB LDS,
// corrupting `tot` and spraying writes past gedges into Wb (absmax 3.4).
// ---------------------------------------------------------------------------
__global__ __launch_bounds__(256) void partition_edges(
    const int* __restrict__ src, const int* __restrict__ dst,
    int* __restrict__ gcur, unsigned int* __restrict__ gedges, int E) {
  __shared__ unsigned int sorted[PBLK_I4 * 4];  // 32 KB
  __shared__ int hist[512], off[512];
  __shared__ int cur[512], gbase[512];
  __shared__ int sc[256];
  __shared__ int tot;
  const int t = threadIdx.x;

  hist[t] = 0;
  hist[256 + t] = 0;
  __syncthreads();

  // ---- load 32 edges/thread into registers, pack, histogram ----
  const int n4    = E >> 2;                 // E divisible by 4 (1.5e6)
  const int base4 = blockIdx.x * PBLK_I4;
  unsigned int pk[32];
#pragma unroll
  for (int k = 0; k < 8; ++k) {
    const int i4 = base4 + k * 256 + t;
    if (i4 < n4) {
      const int4 d4 = ((const int4*)dst)[i4];
      const int4 s4 = ((const int4*)src)[i4];
      pk[k * 4 + 0] = ((unsigned)d4.x << 12) | (unsigned)s4.x;
      pk[k * 4 + 1] = ((unsigned)d4.y << 12) | (unsigned)s4.y;
      pk[k * 4 + 2] = ((unsigned)d4.z << 12) | (unsigned)s4.z;
      pk[k * 4 + 3] = ((unsigned)d4.w << 12) | (unsigned)s4.w;
#pragma unroll
      for (int j = 0; j < 4; ++j)
        atomicAdd(&hist[pk[k * 4 + j] >> 19], 1);
    } else {
#pragma unroll
      for (int j = 0; j < 4; ++j) pk[k * 4 + j] = 0xFFFFFFFFu;
    }
  }
  __syncthreads();

  // ---- exclusive scan of hist[0..511]: pair-sum + Hillis-Steele(256) ----
  const int h0 = hist[2 * t];
  const int h1 = hist[2 * t + 1];
  const int pairsum = h0 + h1;
  sc[t] = pairsum;
  __syncthreads();
#pragma unroll
  for (int o = 1; o < 256; o <<= 1) {
    const int v = (t >= o) ? sc[t - o] : 0;
    __syncthreads();
    sc[t] += v;
    __syncthreads();
  }
  {
    const int excl = sc[t] - pairsum;       // exclusive over pairs
    off[2 * t]     = excl;
    off[2 * t + 1] = excl + h0;
    if (t == 255) tot = sc[255];
  }
  __syncthreads();

  // ---- reserve global ranges, zero local cursors ----
  cur[t] = 0;
  cur[256 + t] = 0;
  for (int i = t; i < 512; i += 256)
    gbase[i] = (i < NBUCKET && hist[i] > 0) ? atomicAdd(&gcur[i], hist[i]) : 0;
  __syncthreads();

  // ---- local scatter: registers -> bucket-sorted LDS ----
#pragma unroll
  for (int k = 0; k < 32; ++k) {
    const unsigned int p = pk[k];
    if (p != 0xFFFFFFFFu) {
      const int b   = p >> 19;
      const int pos = atomicAdd(&cur[b], 1);
      sorted[off[b] + pos] = p;
    }
  }
  __syncthreads();

  // ---- coalesced-run write-out ----
  for (int j = t; j < tot; j += 256) {
    const unsigned int p = sorted[j];
    const int b   = p >> 19;
    const int idx = gbase[b] + (j - off[b]);
    if (idx < CAP) gedges[(size_t)b * CAP + idx] = p;
  }
}

// ---------------------------------------------------------------------------
// bucket_aggregate: one block per bucket (128 cells).  LDS counting sort by
// cell, then register gather-aggregate (half-wave float4) from L2-resident
// y_gene.  Replaces global CSR + aggregate entirely.
// ---------------------------------------------------------------------------
__global__ __launch_bounds__(256) void bucket_aggregate(
    const unsigned int* __restrict__ gedges, const int* __restrict__ gcur,
    const float* __restrict__ y, float* __restrict__ msg) {
  __shared__ unsigned short srt[CAP];          // 7.4 KB: src per edge, cell-sorted
  __shared__ int counts[128], coff[128], ccur[128];
  __shared__ int sc[128];
  const int b = blockIdx.x;
  const int t = threadIdx.x;

  int cnt = gcur[b];
  if (cnt > CAP) cnt = CAP;

  if (t < 128) { counts[t] = 0; ccur[t] = 0; }
  __syncthreads();

  // ---- stage edges into registers + per-cell histogram ----
  unsigned int e[15];                          // 15*256 = 3840 >= CAP
#pragma unroll
  for (int k = 0; k < 15; ++k) {
    const int j = k * 256 + t;
    e[k] = (j < cnt) ? gedges[(size_t)b * CAP + j] : 0xFFFFFFFFu;
    if (e[k] != 0xFFFFFFFFu) atomicAdd(&counts[(e[k] >> 12) & 127], 1);
  }
  __syncthreads();

  // ---- exclusive scan of counts[128] ----
  if (t < 128) sc[t] = counts[t];
  __syncthreads();
#pragma unroll
  for (int o = 1; o < 128; o <<= 1) {
    int v = 0;
    if (t < 128 && t >= o) v = sc[t - o];
    __syncthreads();
    if (t < 128) sc[t] += v;
    __syncthreads();
  }
  if (t < 128) coff[t] = sc[t] - counts[t];
  __syncthreads();

  // ---- scatter src indices into cell-sorted LDS (u16) ----
#pragma unroll
  for (int k = 0; k < 15; ++k) {
    if (e[k] != 0xFFFFFFFFu) {
      const int c   = (e[k] >> 12) & 127;
      const int pos = atomicAdd(&ccur[c], 1);
      srt[coff[c] + pos] = (unsigned short)(e[k] & 0xFFF);
    }
  }
  __syncthreads();

  // ---- per-cell register gather: wave w owns cells [w*32, w*32+32) ----
  const int w    = t >> 6;
  const int lane = t & 63;
  const int half = lane >> 5;
  const int sub  = lane & 31;
  for (int ci = 0; ci < 32; ++ci) {
    const int c     = w * 32 + ci;
    const int gcell = b * 128 + c;
    if (gcell >= N_CELL) break;                // wave-uniform
    const int beg = coff[c], num = counts[c];

    f32x4 a0 = {0.f, 0.f, 0.f, 0.f}, a1 = {0.f, 0.f, 0.f, 0.f};
    int ei = 0;
    for (; ei + 3 < num; ei += 4) {            // 4 edges: 2 per half
      const int s0 = srt[beg + ei + half];
      const int s1 = srt[beg + ei + 2 + half];
      a0 += *(const f32x4*)(y + (size_t)s0 * DIM + sub * 4);
      a1 += *(const f32x4*)(y + (size_t)s1 * DIM + sub * 4);
    }
    if (ei + 1 < num) {                        // 2 edges
      const int s = srt[beg + ei + half];
      a0 += *(const f32x4*)(y + (size_t)s * DIM + sub * 4);
      ei += 2;
    }
    if (ei < num && half == 0) {               // last single edge
      const int s = srt[beg + ei];
      a1 += *(const f32x4*)(y + (size_t)s * DIM + sub * 4);
    }
    f32x4 r = a0 + a1;
    r.x += __shfl_down(r.x, 32);
    r.y += __shfl_down(r.y, 32);
    r.z += __shfl_down(r.z, 32);
    r.w += __shfl_down(r.w, 32);
    if (half == 0) {
      const float ic = 1.0f / fmaxf((float)num, 1.0f);
      *(f32x4*)(msg + (size_t)gcell * DIM + sub * 4) = r * ic;
    }
  }
}

// ---------------------------------------------------------------------------
// main GEMM on matrix cores: out_pre = bf16(x_cell) @ bf16(Wr) + msg + bl,
// fused BN partial sums -> one atomicAdd per thread into stats[0:256].
// ---------------------------------------------------------------------------
__global__ __launch_bounds__(256) void main_gemm_mfma(
    const float* __restrict__ xc, const unsigned short* __restrict__ wb,
    const float* __restrict__ bl, const float* __restrict__ msg,
    float* __restrict__ out, float* __restrict__ stats) {
  __shared__ unsigned short a_lds[128 * 128];  // 32 KB
  __shared__ float ps[4][64], ps2[4][64];      // per-wave BN partials, 2 KB
  const int t    = threadIdx.x;
  const int row0 = blockIdx.x * 128;

  // ---- stage A: fp32 -> bf16, swizzled ----
  {
    const int row  = t >> 1;
    const int h    = t & 1;
    const int grow = row0 + row;
    const bool ok  = grow < N_CELL;
    const float* xrow = xc + (size_t)grow * DIM;
#pragma unroll
    for (int i = 0; i < 4; ++i) {
      const int kk = h * 64 + i * 16;
      float4 f0, f1, f2, f3;
      if (ok) {
        f0 = *(const float4*)(xrow + kk);
        f1 = *(const float4*)(xrow + kk + 4);
        f2 = *(const float4*)(xrow + kk + 8);
        f3 = *(const float4*)(xrow + kk + 12);
      } else {
        f0 = f1 = f2 = f3 = make_float4(0.f, 0.f, 0.f, 0.f);
      }
      const float fv[16] = {f0.x, f0.y, f0.z, f0.w, f1.x, f1.y, f1.z, f1.w,
                            f2.x, f2.y, f2.z, f2.w, f3.x, f3.y, f3.z, f3.w};
      union { unsigned short u[16]; uint4 q[2]; } pk;
#pragma unroll
      for (int e = 0; e < 16; ++e) {
        const __bf16 bb = (__bf16)fv[e];
        pk.u[e] = __builtin_bit_cast(unsigned short, bb);
      }
      const int s0 = ((kk >> 3) + 0) ^ (row & 15);
      const int s1 = ((kk >> 3) + 1) ^ (row & 15);
      *(uint4*)&a_lds[row * 128 + s0 * 8] = pk.q[0];
      *(uint4*)&a_lds[row * 128 + s1 * 8] = pk.q[1];
    }
  }
  __syncthreads();

  const int w   = t >> 6, l = t & 63;
  const int wr  = w >> 1, wc = w & 1;
  const int l15 = l & 15, lq = l >> 4;

  f32x4 acc[4][4];
#pragma unroll
  for (int g = 0; g < 4; ++g)
#pragma unroll
    for (int c = 0; c < 4; ++c) acc[g][c] = (f32x4){0.f, 0.f, 0.f, 0.f};

#pragma unroll
  for (int ks = 0; ks < 4; ++ks) {
    bf16x8 bfr[4];
#pragma unroll
    for (int c = 0; c < 4; ++c)
      bfr[c] = *(const bf16x8*)(wb +
                (size_t)(((ks * 8 + wc * 4 + c) * 64 + l) * 8));
    bf16x8 afr[4];
#pragma unroll
    for (int g = 0; g < 4; ++g) {
      const int row = wr * 64 + g * 16 + l15;   // row & 15 == l15
      const int s   = (ks * 4 + lq) ^ l15;
      afr[g] = *(const bf16x8*)&a_lds[row * 128 + s * 8];
    }
#pragma unroll
    for (int g = 0; g < 4; ++g)
#pragma unroll
      for (int c = 0; c < 4; ++c)
        acc[g][c] = __builtin_amdgcn_mfma_f32_16x16x32_bf16(
            afr[g], bfr[c], acc[g][c], 0, 0, 0);
  }

  // epilogue: + msg + bias, with per-column sum/sumsq accumulation
  float csum[4] = {0.f, 0.f, 0.f, 0.f}, csq[4] = {0.f, 0.f, 0.f, 0.f};
#pragma unroll
  for (int g = 0; g < 4; ++g) {
#pragma unroll
    for (int c = 0; c < 4; ++c) {
      const int col = wc * 64 + c * 16 + l15;
      const float bbl = bl[col];
#pragma unroll
      for (int r = 0; r < 4; ++r) {
        const int grow = row0 + wr * 64 + g * 16 + lq * 4 + r;
        if (grow < N_CELL) {
          const float val =
              acc[g][c][r] + msg[(size_t)grow * DIM + col] + bbl;
          out[(size_t)grow * DIM + col] = val;
          csum[c] += val;
          csq[c]  += val * val;
        }
      }
    }
  }
#pragma unroll
  for (int c = 0; c < 4; ++c) {
    csum[c] += __shfl_xor(csum[c], 16);
    csum[c] += __shfl_xor(csum[c], 32);
    csq[c]  += __shfl_xor(csq[c], 16);
    csq[c]  += __shfl_xor(csq[c], 32);
  }
  if (lq == 0) {
#pragma unroll
    for (int c = 0; c < 4; ++c) {
      ps[w][c * 16 + l15]  = csum[c];
      ps2[w][c * 16 + l15] = csq[c];
    }
  }
  __syncthreads();
  {
    const int which = t >> 7;          // 0: sum, 1: sumsq
    const int col   = t & 127;
    const int wcc   = col >> 6;        // waves wcc and 2+wcc share this col
    const int idx   = col & 63;
    const float v = which ? (ps2[wcc][idx] + ps2[2 + wcc][idx])
                          : (ps[wcc][idx] + ps[2 + wcc][idx]);
    unsafeAtomicAdd(&stats[t], v);     // t in [0,256): sum[128] | sumsq[128]
  }
}

// ---------------------------------------------------------------------------
// bn_finalize: mu / inv_std from accumulated sums (1 block, ~2 us)
// ---------------------------------------------------------------------------
__global__ __launch_bounds__(128) void bn_finalize(float* __restrict__ stats) {
  const int j = threadIdx.x;
  const float mu  = stats[j] / (float)N_CELL;
  const float var = stats[128 + j] / (float)N_CELL - mu * mu;
  stats[256 + j] = mu;
  stats[384 + j] = rsqrtf(var + EPS_BN);
}

// ---------------------------------------------------------------------------
// bn_apply: normalize in place (float4)
// ---------------------------------------------------------------------------
__global__ __launch_bounds__(256) void bn_apply(
    float* __restrict__ out, const float* __restrict__ stats) {
  const size_t total = (size_t)N_CELL * DIM / 4;
  const size_t step  = (size_t)gridDim.x * blockDim.x;
  for (size_t i = (size_t)blockIdx.x * blockDim.x + threadIdx.x; i < total;
       i += step) {
    float4 v = ((float4*)out)[i];
    const int col = (int)((i * 4) & (DIM - 1));
    v.x = (v.x - stats[256 + col + 0]) * stats[384 + col + 0];
    v.y = (v.y - stats[256 + col + 1]) * stats[384 + col + 1];
    v.z = (v.z - stats[256 + col + 2]) * stats[384 + col + 2];
    v.w = (v.w - stats[256 + col + 3]) * stats[384 + col + 3];
    ((float4*)out)[i] = v;
  }
}

// ---------------------------------------------------------------------------
extern "C" void kernel_launch(void* const* d_in, const int* in_sizes, int n_in,
                              void* d_out, int out_size, void* d_ws,
                              size_t ws_size, hipStream_t stream) {
  const float* x_cell = (const float*)d_in[0];
  const float* x_gene = (const float*)d_in[1];
  const float* Wl_gc  = (const float*)d_in[2];
  const float* bl_gc  = (const float*)d_in[3];
  const float* Wr_gc  = (const float*)d_in[4];
  // d_in[5..7] (cg weights) are dead: the gene branch never feeds the output.
  const int* gc_src = (const int*)d_in[8];
  const int* gc_dst = (const int*)d_in[9];
  const int  E      = in_sizes[8];

  const float* Wl1 = Wl_gc + DIM * DIM;   // layer 1 (last)
  const float* bl1 = bl_gc + DIM;
  const float* Wr1 = Wr_gc + DIM * DIM;

  float* ws    = (float*)d_ws;
  float* stats = ws + WS_STATS;
  int*   gcur  = (int*)(ws + WS_GCUR);
  float* msg   = ws + WS_MSG;
  float* ygene = ws + WS_YGENE;
  unsigned int*   gedges = (unsigned int*)(ws + WS_GEDGE);
  unsigned short* Wb     = (unsigned short*)(ws + WS_WB);
  float* out   = (float*)d_out;

  // zero stats + bucket counters (4 KB)
  hipMemsetAsync(d_ws, 0, (size_t)WS_ZERO * sizeof(float), stream);

  conv_w<<<64, 256, 0, stream>>>(Wr1, Wb);
  ygene_gemm<<<N_GENE / 8, 128, 0, stream>>>(x_gene, Wl1, ygene);

  const int npart = (E / 4 + PBLK_I4 - 1) / PBLK_I4;   // 184 blocks
  partition_edges<<<npart, 256, 0, stream>>>(gc_src, gc_dst, gcur, gedges, E);
  bucket_aggregate<<<NBUCKET, 256, 0, stream>>>(gedges, gcur, ygene, msg);

  main_gemm_mfma<<<NB_GEMM, 256, 0, stream>>>(x_cell, Wb, bl1, msg, out,
                                              stats);

  bn_finalize<<<1, 128, 0, stream>>>(stats);
  bn_apply<<<2048, 256, 0, stream>>>(out, stats);
}

// Round 9
// 126.603 us; speedup vs baseline: 2.8301x; 1.0822x over previous
//
#include <hip/hip_runtime.h>

// Problem constants (from reference)
#define N_CELL 60000
#define N_GENE 4000
#define DIM    128
#define EPS_BN 1e-5f

#define NBUCKET 469            // ceil(60000/128) buckets of 128 cells
#define CAP     3700           // per-bucket capacity: mean 3200, +8.8 sigma
#define CAP_Q   1024           // per-quarter capacity: mean 800, +8 sigma
#define PBLK_I4 2048           // int4s per partition block (= 8192 edges)
#define NB_GEMM ((N_CELL + 127) / 128)   // 469 main-GEMM blocks

// Workspace layout (4-byte words).  Zeroed region = first WS_ZERO words.
//   stats  [512]            @ 0        (sum,sumsq,mu,istd — 128 each)
//   gcur   [512]            @ 512      (int; per-bucket edge counters, 469 used)
//   --- end of zeroed region (1024 words) ---
//   msg    [N_CELL*DIM]     @ 1024               -> ends 7,681,024
//   ygene  [N_GENE*DIM]     @ 7,681,024          -> ends 8,193,024
//   gedges [NBUCKET*CAP]    @ 8,193,024 (u32)    -> ends 9,928,324
//   Wb     [16384 bf16]     @ 9,928,324 (8192 w) -> ends 9,936,516
// total 9,936,516 words = 39.75 MB
#define WS_STATS  0
#define WS_GCUR   512
#define WS_ZERO   1024
#define WS_MSG    1024
#define WS_YGENE  7681024
#define WS_GEDGE  8193024
#define WS_WB     9928324

typedef __bf16 bf16x8 __attribute__((ext_vector_type(8)));
typedef float  f32x4  __attribute__((ext_vector_type(4)));

// ---------------------------------------------------------------------------
// Kernel 1: y_gene = x_gene @ Wl (fp32 — small, keeps aggregate path exact)
// ---------------------------------------------------------------------------
__global__ __launch_bounds__(128) void ygene_gemm(
    const float* __restrict__ xg, const float* __restrict__ Wl,
    float* __restrict__ y) {
  const int j  = threadIdx.x;
  const int r0 = blockIdx.x * 8;
  float acc[8] = {};
  for (int k = 0; k < DIM; ++k) {
    const float w = Wl[k * DIM + j];
#pragma unroll
    for (int r = 0; r < 8; ++r)
      acc[r] += xg[(size_t)(r0 + r) * DIM + k] * w;
  }
#pragma unroll
  for (int r = 0; r < 8; ++r)
    y[(size_t)(r0 + r) * DIM + j] = acc[r];
}

// ---------------------------------------------------------------------------
// conv_w: Wr fp32 [128k][128j] -> fragment-ordered bf16 for 16x16x32 MFMA.
// ---------------------------------------------------------------------------
__global__ __launch_bounds__(256) void conv_w(
    const float* __restrict__ w, unsigned short* __restrict__ wb) {
  const int i = blockIdx.x * 256 + threadIdx.x;  // 0..16383
  const int k = i >> 7, j = i & 127;
  const int chunk = (k >> 5) * 8 + (j >> 4);
  const int lane  = ((k >> 3) & 3) * 16 + (j & 15);
  const int e     = k & 7;
  const __bf16 b  = (__bf16)w[i];
  wb[(chunk * 64 + lane) * 8 + e] = __builtin_bit_cast(unsigned short, b);
}

// ---------------------------------------------------------------------------
// partition_edges: pack (dst<<12 | src) and counting-sort 8192-edge chunks
// into 469 global bucket regions (bucket = dst>>7).  LDS-local sort makes
// the global writes contiguous runs instead of random 4 B scatters.
// hist/off/cur/gbase sized 512 and FULLY zeroed (R8 fix: scan reads 0..511).
// ---------------------------------------------------------------------------
__global__ __launch_bounds__(256) void partition_edges(
    const int* __restrict__ src, const int* __restrict__ dst,
    int* __restrict__ gcur, unsigned int* __restrict__ gedges, int E) {
  __shared__ unsigned int sorted[PBLK_I4 * 4];  // 32 KB
  __shared__ int hist[512], off[512];
  __shared__ int cur[512], gbase[512];
  __shared__ int sc[256];
  __shared__ int tot;
  const int t = threadIdx.x;

  hist[t] = 0;
  hist[256 + t] = 0;
  __syncthreads();

  // ---- load 32 edges/thread into registers, pack, histogram ----
  const int n4    = E >> 2;                 // E divisible by 4 (1.5e6)
  const int base4 = blockIdx.x * PBLK_I4;
  unsigned int pk[32];
#pragma unroll
  for (int k = 0; k < 8; ++k) {
    const int i4 = base4 + k * 256 + t;
    if (i4 < n4) {
      const int4 d4 = ((const int4*)dst)[i4];
      const int4 s4 = ((const int4*)src)[i4];
      pk[k * 4 + 0] = ((unsigned)d4.x << 12) | (unsigned)s4.x;
      pk[k * 4 + 1] = ((unsigned)d4.y << 12) | (unsigned)s4.y;
      pk[k * 4 + 2] = ((unsigned)d4.z << 12) | (unsigned)s4.z;
      pk[k * 4 + 3] = ((unsigned)d4.w << 12) | (unsigned)s4.w;
#pragma unroll
      for (int j = 0; j < 4; ++j)
        atomicAdd(&hist[pk[k * 4 + j] >> 19], 1);
    } else {
#pragma unroll
      for (int j = 0; j < 4; ++j) pk[k * 4 + j] = 0xFFFFFFFFu;
    }
  }
  __syncthreads();

  // ---- exclusive scan of hist[0..511]: pair-sum + Hillis-Steele(256) ----
  const int h0 = hist[2 * t];
  const int h1 = hist[2 * t + 1];
  const int pairsum = h0 + h1;
  sc[t] = pairsum;
  __syncthreads();
#pragma unroll
  for (int o = 1; o < 256; o <<= 1) {
    const int v = (t >= o) ? sc[t - o] : 0;
    __syncthreads();
    sc[t] += v;
    __syncthreads();
  }
  {
    const int excl = sc[t] - pairsum;       // exclusive over pairs
    off[2 * t]     = excl;
    off[2 * t + 1] = excl + h0;
    if (t == 255) tot = sc[255];
  }
  __syncthreads();

  // ---- reserve global ranges, zero local cursors ----
  cur[t] = 0;
  cur[256 + t] = 0;
  for (int i = t; i < 512; i += 256)
    gbase[i] = (i < NBUCKET && hist[i] > 0) ? atomicAdd(&gcur[i], hist[i]) : 0;
  __syncthreads();

  // ---- local scatter: registers -> bucket-sorted LDS ----
#pragma unroll
  for (int k = 0; k < 32; ++k) {
    const unsigned int p = pk[k];
    if (p != 0xFFFFFFFFu) {
      const int b   = p >> 19;
      const int pos = atomicAdd(&cur[b], 1);
      sorted[off[b] + pos] = p;
    }
  }
  __syncthreads();

  // ---- coalesced-run write-out ----
  for (int j = t; j < tot; j += 256) {
    const unsigned int p = sorted[j];
    const int b   = p >> 19;
    const int idx = gbase[b] + (j - off[b]);
    if (idx < CAP) gedges[(size_t)b * CAP + idx] = p;
  }
}

// ---------------------------------------------------------------------------
// bucket_aggregate: FOUR blocks per bucket, each owning a 32-cell quarter
// (R9: 469 blocks -> 1876, occupancy 17% -> ~90% of wave slots; each wave
// gathers 8 cells instead of 32).  Block re-stages the bucket's packed
// edges (L2 re-read, cheap), filters to its quarter, LDS counting sort,
// then register gather from L2-resident y_gene.
// ---------------------------------------------------------------------------
__global__ __launch_bounds__(256) void bucket_aggregate(
    const unsigned int* __restrict__ gedges, const int* __restrict__ gcur,
    const float* __restrict__ y, float* __restrict__ msg) {
  __shared__ unsigned short srt[CAP_Q];        // 2 KB: src per edge, cell-sorted
  __shared__ int counts[32], coff[32], ccur[32];
  __shared__ int sc[32];
  const int b = blockIdx.x >> 2;               // bucket
  const int q = blockIdx.x & 3;                // quarter (32 cells)
  const int t = threadIdx.x;

  int cnt = gcur[b];
  if (cnt > CAP) cnt = CAP;

  if (t < 32) { counts[t] = 0; ccur[t] = 0; }
  __syncthreads();

  // ---- stage bucket edges, keep only our quarter, histogram ----
  unsigned int e[15];                          // 15*256 = 3840 >= CAP
#pragma unroll
  for (int k = 0; k < 15; ++k) {
    const int j = k * 256 + t;
    unsigned int v = (j < cnt) ? gedges[(size_t)b * CAP + j] : 0xFFFFFFFFu;
    // cell = (v>>12)&127; quarter = cell>>5 = (v>>17)&3
    if (v != 0xFFFFFFFFu && (int)((v >> 17) & 3) == q) {
      e[k] = v;
      atomicAdd(&counts[(v >> 12) & 31], 1);
    } else {
      e[k] = 0xFFFFFFFFu;
    }
  }
  __syncthreads();

  // ---- exclusive scan of counts[32] ----
  if (t < 32) sc[t] = counts[t];
  __syncthreads();
#pragma unroll
  for (int o = 1; o < 32; o <<= 1) {
    int v = 0;
    if (t < 32 && t >= o) v = sc[t - o];
    __syncthreads();
    if (t < 32) sc[t] += v;
    __syncthreads();
  }
  if (t < 32) coff[t] = sc[t] - counts[t];
  __syncthreads();

  // ---- scatter src indices into cell-sorted LDS (u16) ----
#pragma unroll
  for (int k = 0; k < 15; ++k) {
    if (e[k] != 0xFFFFFFFFu) {
      const int c   = (e[k] >> 12) & 31;
      const int pos = atomicAdd(&ccur[c], 1);
      const int idx = coff[c] + pos;
      if (idx < CAP_Q) srt[idx] = (unsigned short)(e[k] & 0xFFF);
    }
  }
  __syncthreads();

  // ---- per-cell register gather: wave w owns cells [w*8, w*8+8) ----
  const int w    = t >> 6;
  const int lane = t & 63;
  const int half = lane >> 5;
  const int sub  = lane & 31;
  for (int ci = 0; ci < 8; ++ci) {
    const int c     = w * 8 + ci;                  // cell within quarter
    const int gcell = b * 128 + q * 32 + c;
    if (gcell >= N_CELL) break;                    // wave-uniform
    const int beg = coff[c], num = counts[c];

    f32x4 a0 = {0.f, 0.f, 0.f, 0.f}, a1 = {0.f, 0.f, 0.f, 0.f};
    int ei = 0;
    for (; ei + 3 < num; ei += 4) {                // 4 edges: 2 per half
      const int s0 = srt[beg + ei + half];
      const int s1 = srt[beg + ei + 2 + half];
      a0 += *(const f32x4*)(y + (size_t)s0 * DIM + sub * 4);
      a1 += *(const f32x4*)(y + (size_t)s1 * DIM + sub * 4);
    }
    if (ei + 1 < num) {                            // 2 edges
      const int s = srt[beg + ei + half];
      a0 += *(const f32x4*)(y + (size_t)s * DIM + sub * 4);
      ei += 2;
    }
    if (ei < num && half == 0) {                   // last single edge
      const int s = srt[beg + ei];
      a1 += *(const f32x4*)(y + (size_t)s * DIM + sub * 4);
    }
    f32x4 r = a0 + a1;
    r.x += __shfl_down(r.x, 32);
    r.y += __shfl_down(r.y, 32);
    r.z += __shfl_down(r.z, 32);
    r.w += __shfl_down(r.w, 32);
    if (half == 0) {
      const float ic = 1.0f / fmaxf((float)num, 1.0f);
      *(f32x4*)(msg + (size_t)gcell * DIM + sub * 4) = r * ic;
    }
  }
}

// ---------------------------------------------------------------------------
// main GEMM on matrix cores: out_pre = bf16(x_cell) @ bf16(Wr) + msg + bl,
// fused BN partial sums -> one atomicAdd per thread into stats[0:256].
// ---------------------------------------------------------------------------
__global__ __launch_bounds__(256) void main_gemm_mfma(
    const float* __restrict__ xc, const unsigned short* __restrict__ wb,
    const float* __restrict__ bl, const float* __restrict__ msg,
    float* __restrict__ out, float* __restrict__ stats) {
  __shared__ unsigned short a_lds[128 * 128];  // 32 KB
  __shared__ float ps[4][64], ps2[4][64];      // per-wave BN partials, 2 KB
  const int t    = threadIdx.x;
  const int row0 = blockIdx.x * 128;

  // ---- stage A: fp32 -> bf16, swizzled ----
  {
    const int row  = t >> 1;
    const int h    = t & 1;
    const int grow = row0 + row;
    const bool ok  = grow < N_CELL;
    const float* xrow = xc + (size_t)grow * DIM;
#pragma unroll
    for (int i = 0; i < 4; ++i) {
      const int kk = h * 64 + i * 16;
      float4 f0, f1, f2, f3;
      if (ok) {
        f0 = *(const float4*)(xrow + kk);
        f1 = *(const float4*)(xrow + kk + 4);
        f2 = *(const float4*)(xrow + kk + 8);
        f3 = *(const float4*)(xrow + kk + 12);
      } else {
        f0 = f1 = f2 = f3 = make_float4(0.f, 0.f, 0.f, 0.f);
      }
      const float fv[16] = {f0.x, f0.y, f0.z, f0.w, f1.x, f1.y, f1.z, f1.w,
                            f2.x, f2.y, f2.z, f2.w, f3.x, f3.y, f3.z, f3.w};
      union { unsigned short u[16]; uint4 q[2]; } pk;
#pragma unroll
      for (int e = 0; e < 16; ++e) {
        const __bf16 bb = (__bf16)fv[e];
        pk.u[e] = __builtin_bit_cast(unsigned short, bb);
      }
      const int s0 = ((kk >> 3) + 0) ^ (row & 15);
      const int s1 = ((kk >> 3) + 1) ^ (row & 15);
      *(uint4*)&a_lds[row * 128 + s0 * 8] = pk.q[0];
      *(uint4*)&a_lds[row * 128 + s1 * 8] = pk.q[1];
    }
  }
  __syncthreads();

  const int w   = t >> 6, l = t & 63;
  const int wr  = w >> 1, wc = w & 1;
  const int l15 = l & 15, lq = l >> 4;

  f32x4 acc[4][4];
#pragma unroll
  for (int g = 0; g < 4; ++g)
#pragma unroll
    for (int c = 0; c < 4; ++c) acc[g][c] = (f32x4){0.f, 0.f, 0.f, 0.f};

#pragma unroll
  for (int ks = 0; ks < 4; ++ks) {
    bf16x8 bfr[4];
#pragma unroll
    for (int c = 0; c < 4; ++c)
      bfr[c] = *(const bf16x8*)(wb +
                (size_t)(((ks * 8 + wc * 4 + c) * 64 + l) * 8));
    bf16x8 afr[4];
#pragma unroll
    for (int g = 0; g < 4; ++g) {
      const int row = wr * 64 + g * 16 + l15;   // row & 15 == l15
      const int s   = (ks * 4 + lq) ^ l15;
      afr[g] = *(const bf16x8*)&a_lds[row * 128 + s * 8];
    }
#pragma unroll
    for (int g = 0; g < 4; ++g)
#pragma unroll
      for (int c = 0; c < 4; ++c)
        acc[g][c] = __builtin_amdgcn_mfma_f32_16x16x32_bf16(
            afr[g], bfr[c], acc[g][c], 0, 0, 0);
  }

  // epilogue: + msg + bias, with per-column sum/sumsq accumulation
  float csum[4] = {0.f, 0.f, 0.f, 0.f}, csq[4] = {0.f, 0.f, 0.f, 0.f};
#pragma unroll
  for (int g = 0; g < 4; ++g) {
#pragma unroll
    for (int c = 0; c < 4; ++c) {
      const int col = wc * 64 + c * 16 + l15;
      const float bbl = bl[col];
#pragma unroll
      for (int r = 0; r < 4; ++r) {
        const int grow = row0 + wr * 64 + g * 16 + lq * 4 + r;
        if (grow < N_CELL) {
          const float val =
              acc[g][c][r] + msg[(size_t)grow * DIM + col] + bbl;
          out[(size_t)grow * DIM + col] = val;
          csum[c] += val;
          csq[c]  += val * val;
        }
      }
    }
  }
#pragma unroll
  for (int c = 0; c < 4; ++c) {
    csum[c] += __shfl_xor(csum[c], 16);
    csum[c] += __shfl_xor(csum[c], 32);
    csq[c]  += __shfl_xor(csq[c], 16);
    csq[c]  += __shfl_xor(csq[c], 32);
  }
  if (lq == 0) {
#pragma unroll
    for (int c = 0; c < 4; ++c) {
      ps[w][c * 16 + l15]  = csum[c];
      ps2[w][c * 16 + l15] = csq[c];
    }
  }
  __syncthreads();
  {
    const int which = t >> 7;          // 0: sum, 1: sumsq
    const int col   = t & 127;
    const int wcc   = col >> 6;        // waves wcc and 2+wcc share this col
    const int idx   = col & 63;
    const float v = which ? (ps2[wcc][idx] + ps2[2 + wcc][idx])
                          : (ps[wcc][idx] + ps[2 + wcc][idx]);
    unsafeAtomicAdd(&stats[t], v);     // t in [0,256): sum[128] | sumsq[128]
  }
}

// ---------------------------------------------------------------------------
// bn_finalize: mu / inv_std from accumulated sums (1 block, ~2 us)
// ---------------------------------------------------------------------------
__global__ __launch_bounds__(128) void bn_finalize(float* __restrict__ stats) {
  const int j = threadIdx.x;
  const float mu  = stats[j] / (float)N_CELL;
  const float var = stats[128 + j] / (float)N_CELL - mu * mu;
  stats[256 + j] = mu;
  stats[384 + j] = rsqrtf(var + EPS_BN);
}

// ---------------------------------------------------------------------------
// bn_apply: normalize in place (float4)
// ---------------------------------------------------------------------------
__global__ __launch_bounds__(256) void bn_apply(
    float* __restrict__ out, const float* __restrict__ stats) {
  const size_t total = (size_t)N_CELL * DIM / 4;
  const size_t step  = (size_t)gridDim.x * blockDim.x;
  for (size_t i = (size_t)blockIdx.x * blockDim.x + threadIdx.x; i < total;
       i += step) {
    float4 v = ((float4*)out)[i];
    const int col = (int)((i * 4) & (DIM - 1));
    v.x = (v.x - stats[256 + col + 0]) * stats[384 + col + 0];
    v.y = (v.y - stats[256 + col + 1]) * stats[384 + col + 1];
    v.z = (v.z - stats[256 + col + 2]) * stats[384 + col + 2];
    v.w = (v.w - stats[256 + col + 3]) * stats[384 + col + 3];
    ((float4*)out)[i] = v;
  }
}

// ---------------------------------------------------------------------------
extern "C" void kernel_launch(void* const* d_in, const int* in_sizes, int n_in,
                              void* d_out, int out_size, void* d_ws,
                              size_t ws_size, hipStream_t stream) {
  const float* x_cell = (const float*)d_in[0];
  const float* x_gene = (const float*)d_in[1];
  const float* Wl_gc  = (const float*)d_in[2];
  const float* bl_gc  = (const float*)d_in[3];
  const float* Wr_gc  = (const float*)d_in[4];
  // d_in[5..7] (cg weights) are dead: the gene branch never feeds the output.
  const int* gc_src = (const int*)d_in[8];
  const int* gc_dst = (const int*)d_in[9];
  const int  E      = in_sizes[8];

  const float* Wl1 = Wl_gc + DIM * DIM;   // layer 1 (last)
  const float* bl1 = bl_gc + DIM;
  const float* Wr1 = Wr_gc + DIM * DIM;

  float* ws    = (float*)d_ws;
  float* stats = ws + WS_STATS;
  int*   gcur  = (int*)(ws + WS_GCUR);
  float* msg   = ws + WS_MSG;
  float* ygene = ws + WS_YGENE;
  unsigned int*   gedges = (unsigned int*)(ws + WS_GEDGE);
  unsigned short* Wb     = (unsigned short*)(ws + WS_WB);
  float* out   = (float*)d_out;

  // zero stats + bucket counters (4 KB)
  hipMemsetAsync(d_ws, 0, (size_t)WS_ZERO * sizeof(float), stream);

  conv_w<<<64, 256, 0, stream>>>(Wr1, Wb);
  ygene_gemm<<<N_GENE / 8, 128, 0, stream>>>(x_gene, Wl1, ygene);

  const int npart = (E / 4 + PBLK_I4 - 1) / PBLK_I4;   // 184 blocks
  partition_edges<<<npart, 256, 0, stream>>>(gc_src, gc_dst, gcur, gedges, E);
  bucket_aggregate<<<NBUCKET * 4, 256, 0, stream>>>(gedges, gcur, ygene, msg);

  main_gemm_mfma<<<NB_GEMM, 256, 0, stream>>>(x_cell, Wb, bl1, msg, out,
                                              stats);

  bn_finalize<<<1, 128, 0, stream>>>(stats);
  bn_apply<<<2048, 256, 0, stream>>>(out, stats);
}

// Round 10
// 124.952 us; speedup vs baseline: 2.8675x; 1.0132x over previous
//
#include <hip/hip_runtime.h>

// Problem constants (from reference)
#define N_CELL 60000
#define N_GENE 4000
#define DIM    128
#define EPS_BN 1e-5f

#define NBUCKET 469            // ceil(60000/128) buckets of 128 cells
#define CAP     3700           // per-bucket capacity: mean 3200, +8.8 sigma
#define CAP_Q   1024           // per-quarter capacity: mean 800, +8 sigma
#define PBLK_I4 2048           // int4s per partition block (= 8192 edges)
#define NB_GEMM ((N_CELL + 127) / 128)   // 469 main-GEMM blocks

// Workspace layout (4-byte words).  Zeroed region = first WS_ZERO words.
//   stats  [512]            @ 0        (sum,sumsq,mu,istd — 128 each)
//   gcur   [512]            @ 512      (int; per-bucket edge counters, 469 used)
//   --- end of zeroed region (1024 words) ---
//   msg    [N_CELL*DIM]     @ 1024               -> ends 7,681,024
//   ygene  [N_GENE*DIM bf16]@ 7,681,024 (256K w) -> ends 7,937,024
//   gedges [NBUCKET*CAP]    @ 8,193,024 (u32)    -> ends 9,928,324
//   Wb     [16384 bf16]     @ 9,928,324 (8192 w) -> ends 9,936,516
// total 9,936,516 words = 39.75 MB
#define WS_STATS  0
#define WS_GCUR   512
#define WS_ZERO   1024
#define WS_MSG    1024
#define WS_YGENE  7681024
#define WS_GEDGE  8193024
#define WS_WB     9928324

typedef __bf16 bf16x8 __attribute__((ext_vector_type(8)));
typedef float  f32x4  __attribute__((ext_vector_type(4)));

__device__ __forceinline__ float bflo(unsigned int u) {
  return __uint_as_float(u << 16);
}
__device__ __forceinline__ float bfhi(unsigned int u) {
  return __uint_as_float(u & 0xFFFF0000u);
}

// ---------------------------------------------------------------------------
// Kernel 1: y_gene = bf16(x_gene @ Wl)  — fp32 accumulate, bf16 store.
// R10: bf16 output halves the aggregate gather's L2 traffic (768->384 MB).
// ---------------------------------------------------------------------------
__global__ __launch_bounds__(128) void ygene_gemm(
    const float* __restrict__ xg, const float* __restrict__ Wl,
    unsigned short* __restrict__ y) {
  const int j  = threadIdx.x;
  const int r0 = blockIdx.x * 8;
  float acc[8] = {};
  for (int k = 0; k < DIM; ++k) {
    const float w = Wl[k * DIM + j];
#pragma unroll
    for (int r = 0; r < 8; ++r)
      acc[r] += xg[(size_t)(r0 + r) * DIM + k] * w;
  }
#pragma unroll
  for (int r = 0; r < 8; ++r) {
    const __bf16 b = (__bf16)acc[r];
    y[(size_t)(r0 + r) * DIM + j] = __builtin_bit_cast(unsigned short, b);
  }
}

// ---------------------------------------------------------------------------
// conv_w: Wr fp32 [128k][128j] -> fragment-ordered bf16 for 16x16x32 MFMA.
// ---------------------------------------------------------------------------
__global__ __launch_bounds__(256) void conv_w(
    const float* __restrict__ w, unsigned short* __restrict__ wb) {
  const int i = blockIdx.x * 256 + threadIdx.x;  // 0..16383
  const int k = i >> 7, j = i & 127;
  const int chunk = (k >> 5) * 8 + (j >> 4);
  const int lane  = ((k >> 3) & 3) * 16 + (j & 15);
  const int e     = k & 7;
  const __bf16 b  = (__bf16)w[i];
  wb[(chunk * 64 + lane) * 8 + e] = __builtin_bit_cast(unsigned short, b);
}

// ---------------------------------------------------------------------------
// partition_edges: pack (dst<<12 | src) and counting-sort 8192-edge chunks
// into 469 global bucket regions (bucket = dst>>7).  LDS-local sort makes
// the global writes contiguous runs instead of random 4 B scatters.
// hist/off/cur/gbase sized 512 and FULLY zeroed (scan reads 0..511).
// ---------------------------------------------------------------------------
__global__ __launch_bounds__(256) void partition_edges(
    const int* __restrict__ src, const int* __restrict__ dst,
    int* __restrict__ gcur, unsigned int* __restrict__ gedges, int E) {
  __shared__ unsigned int sorted[PBLK_I4 * 4];  // 32 KB
  __shared__ int hist[512], off[512];
  __shared__ int cur[512], gbase[512];
  __shared__ int sc[256];
  __shared__ int tot;
  const int t = threadIdx.x;

  hist[t] = 0;
  hist[256 + t] = 0;
  __syncthreads();

  // ---- load 32 edges/thread into registers, pack, histogram ----
  const int n4    = E >> 2;                 // E divisible by 4 (1.5e6)
  const int base4 = blockIdx.x * PBLK_I4;
  unsigned int pk[32];
#pragma unroll
  for (int k = 0; k < 8; ++k) {
    const int i4 = base4 + k * 256 + t;
    if (i4 < n4) {
      const int4 d4 = ((const int4*)dst)[i4];
      const int4 s4 = ((const int4*)src)[i4];
      pk[k * 4 + 0] = ((unsigned)d4.x << 12) | (unsigned)s4.x;
      pk[k * 4 + 1] = ((unsigned)d4.y << 12) | (unsigned)s4.y;
      pk[k * 4 + 2] = ((unsigned)d4.z << 12) | (unsigned)s4.z;
      pk[k * 4 + 3] = ((unsigned)d4.w << 12) | (unsigned)s4.w;
#pragma unroll
      for (int j = 0; j < 4; ++j)
        atomicAdd(&hist[pk[k * 4 + j] >> 19], 1);
    } else {
#pragma unroll
      for (int j = 0; j < 4; ++j) pk[k * 4 + j] = 0xFFFFFFFFu;
    }
  }
  __syncthreads();

  // ---- exclusive scan of hist[0..511]: pair-sum + Hillis-Steele(256) ----
  const int h0 = hist[2 * t];
  const int h1 = hist[2 * t + 1];
  const int pairsum = h0 + h1;
  sc[t] = pairsum;
  __syncthreads();
#pragma unroll
  for (int o = 1; o < 256; o <<= 1) {
    const int v = (t >= o) ? sc[t - o] : 0;
    __syncthreads();
    sc[t] += v;
    __syncthreads();
  }
  {
    const int excl = sc[t] - pairsum;       // exclusive over pairs
    off[2 * t]     = excl;
    off[2 * t + 1] = excl + h0;
    if (t == 255) tot = sc[255];
  }
  __syncthreads();

  // ---- reserve global ranges, zero local cursors ----
  cur[t] = 0;
  cur[256 + t] = 0;
  for (int i = t; i < 512; i += 256)
    gbase[i] = (i < NBUCKET && hist[i] > 0) ? atomicAdd(&gcur[i], hist[i]) : 0;
  __syncthreads();

  // ---- local scatter: registers -> bucket-sorted LDS ----
#pragma unroll
  for (int k = 0; k < 32; ++k) {
    const unsigned int p = pk[k];
    if (p != 0xFFFFFFFFu) {
      const int b   = p >> 19;
      const int pos = atomicAdd(&cur[b], 1);
      sorted[off[b] + pos] = p;
    }
  }
  __syncthreads();

  // ---- coalesced-run write-out ----
  for (int j = t; j < tot; j += 256) {
    const unsigned int p = sorted[j];
    const int b   = p >> 19;
    const int idx = gbase[b] + (j - off[b]);
    if (idx < CAP) gedges[(size_t)b * CAP + idx] = p;
  }
}

// ---------------------------------------------------------------------------
// bucket_aggregate: 4 blocks per bucket (32-cell quarters).  Block re-stages
// the bucket's packed edges, filters to its quarter, LDS counting sort, then
// bf16 register gather from L2-resident y_gene.
// R10 gather layout: 16 lanes per edge (bf16x8 = 16 B per lane, 8 dims),
// 4 edge-groups per wave on the SAME cell, shfl_xor(16/32) combine.
// ---------------------------------------------------------------------------
__global__ __launch_bounds__(256) void bucket_aggregate(
    const unsigned int* __restrict__ gedges, const int* __restrict__ gcur,
    const unsigned short* __restrict__ yb, float* __restrict__ msg) {
  __shared__ unsigned short srt[CAP_Q];        // 2 KB: src per edge, cell-sorted
  __shared__ int counts[32], coff[32], ccur[32];
  __shared__ int sc[32];
  const int b = blockIdx.x >> 2;               // bucket
  const int q = blockIdx.x & 3;                // quarter (32 cells)
  const int t = threadIdx.x;

  int cnt = gcur[b];
  if (cnt > CAP) cnt = CAP;

  if (t < 32) { counts[t] = 0; ccur[t] = 0; }
  __syncthreads();

  // ---- stage bucket edges, keep only our quarter, histogram ----
  unsigned int e[15];                          // 15*256 = 3840 >= CAP
#pragma unroll
  for (int k = 0; k < 15; ++k) {
    const int j = k * 256 + t;
    unsigned int v = (j < cnt) ? gedges[(size_t)b * CAP + j] : 0xFFFFFFFFu;
    // cell = (v>>12)&127; quarter = cell>>5 = (v>>17)&3
    if (v != 0xFFFFFFFFu && (int)((v >> 17) & 3) == q) {
      e[k] = v;
      atomicAdd(&counts[(v >> 12) & 31], 1);
    } else {
      e[k] = 0xFFFFFFFFu;
    }
  }
  __syncthreads();

  // ---- exclusive scan of counts[32] ----
  if (t < 32) sc[t] = counts[t];
  __syncthreads();
#pragma unroll
  for (int o = 1; o < 32; o <<= 1) {
    int v = 0;
    if (t < 32 && t >= o) v = sc[t - o];
    __syncthreads();
    if (t < 32) sc[t] += v;
    __syncthreads();
  }
  if (t < 32) coff[t] = sc[t] - counts[t];
  __syncthreads();

  // ---- scatter src indices into cell-sorted LDS (u16) ----
#pragma unroll
  for (int k = 0; k < 15; ++k) {
    if (e[k] != 0xFFFFFFFFu) {
      const int c   = (e[k] >> 12) & 31;
      const int pos = atomicAdd(&ccur[c], 1);
      const int idx = coff[c] + pos;
      if (idx < CAP_Q) srt[idx] = (unsigned short)(e[k] & 0xFFF);
    }
  }
  __syncthreads();

  // ---- per-cell bf16 gather: wave w owns cells [w*8, w*8+8) ----
  const int w    = t >> 6;
  const int lane = t & 63;
  const int grp  = lane >> 4;                  // edge group 0..3
  const int lsub = lane & 15;                  // 8-dim slice: dims lsub*8..+8
  for (int ci = 0; ci < 8; ++ci) {
    const int c     = w * 8 + ci;                  // cell within quarter
    const int gcell = b * 128 + q * 32 + c;
    if (gcell >= N_CELL) break;                    // wave-uniform
    const int beg = coff[c], num = counts[c];

    float a0[8] = {}, a1[8] = {};
    int ei = grp;
    for (; ei + 4 < num; ei += 8) {                // 2-deep, 4 groups
      const int s0 = srt[beg + ei];
      const int s1 = srt[beg + ei + 4];
      const uint4 v0 = *(const uint4*)(yb + (size_t)s0 * DIM + lsub * 8);
      const uint4 v1 = *(const uint4*)(yb + (size_t)s1 * DIM + lsub * 8);
      a0[0] += bflo(v0.x); a0[1] += bfhi(v0.x);
      a0[2] += bflo(v0.y); a0[3] += bfhi(v0.y);
      a0[4] += bflo(v0.z); a0[5] += bfhi(v0.z);
      a0[6] += bflo(v0.w); a0[7] += bfhi(v0.w);
      a1[0] += bflo(v1.x); a1[1] += bfhi(v1.x);
      a1[2] += bflo(v1.y); a1[3] += bfhi(v1.y);
      a1[4] += bflo(v1.z); a1[5] += bfhi(v1.z);
      a1[6] += bflo(v1.w); a1[7] += bfhi(v1.w);
    }
    if (ei < num) {                                // tail edge for this group
      const int s = srt[beg + ei];
      const uint4 v = *(const uint4*)(yb + (size_t)s * DIM + lsub * 8);
      a0[0] += bflo(v.x); a0[1] += bfhi(v.x);
      a0[2] += bflo(v.y); a0[3] += bfhi(v.y);
      a0[4] += bflo(v.z); a0[5] += bfhi(v.z);
      a0[6] += bflo(v.w); a0[7] += bfhi(v.w);
    }
    // combine the 4 edge-groups (lanes xor 16, xor 32 share lsub)
    float r[8];
#pragma unroll
    for (int d = 0; d < 8; ++d) {
      float s = a0[d] + a1[d];
      s += __shfl_xor(s, 16);
      s += __shfl_xor(s, 32);
      r[d] = s;
    }
    if (grp == 0) {
      const float ic = 1.0f / fmaxf((float)num, 1.0f);
      float* mrow = msg + (size_t)gcell * DIM + lsub * 8;
      *(f32x4*)(mrow)     = (f32x4){r[0] * ic, r[1] * ic, r[2] * ic, r[3] * ic};
      *(f32x4*)(mrow + 4) = (f32x4){r[4] * ic, r[5] * ic, r[6] * ic, r[7] * ic};
    }
  }
}

// ---------------------------------------------------------------------------
// main GEMM on matrix cores: out_pre = bf16(x_cell) @ bf16(Wr) + msg + bl,
// fused BN partial sums -> one atomicAdd per thread into stats[0:256].
// ---------------------------------------------------------------------------
__global__ __launch_bounds__(256) void main_gemm_mfma(
    const float* __restrict__ xc, const unsigned short* __restrict__ wb,
    const float* __restrict__ bl, const float* __restrict__ msg,
    float* __restrict__ out, float* __restrict__ stats) {
  __shared__ unsigned short a_lds[128 * 128];  // 32 KB
  __shared__ float ps[4][64], ps2[4][64];      // per-wave BN partials, 2 KB
  const int t    = threadIdx.x;
  const int row0 = blockIdx.x * 128;

  // ---- stage A: fp32 -> bf16, swizzled ----
  {
    const int row  = t >> 1;
    const int h    = t & 1;
    const int grow = row0 + row;
    const bool ok  = grow < N_CELL;
    const float* xrow = xc + (size_t)grow * DIM;
#pragma unroll
    for (int i = 0; i < 4; ++i) {
      const int kk = h * 64 + i * 16;
      float4 f0, f1, f2, f3;
      if (ok) {
        f0 = *(const float4*)(xrow + kk);
        f1 = *(const float4*)(xrow + kk + 4);
        f2 = *(const float4*)(xrow + kk + 8);
        f3 = *(const float4*)(xrow + kk + 12);
      } else {
        f0 = f1 = f2 = f3 = make_float4(0.f, 0.f, 0.f, 0.f);
      }
      const float fv[16] = {f0.x, f0.y, f0.z, f0.w, f1.x, f1.y, f1.z, f1.w,
                            f2.x, f2.y, f2.z, f2.w, f3.x, f3.y, f3.z, f3.w};
      union { unsigned short u[16]; uint4 q[2]; } pk;
#pragma unroll
      for (int e = 0; e < 16; ++e) {
        const __bf16 bb = (__bf16)fv[e];
        pk.u[e] = __builtin_bit_cast(unsigned short, bb);
      }
      const int s0 = ((kk >> 3) + 0) ^ (row & 15);
      const int s1 = ((kk >> 3) + 1) ^ (row & 15);
      *(uint4*)&a_lds[row * 128 + s0 * 8] = pk.q[0];
      *(uint4*)&a_lds[row * 128 + s1 * 8] = pk.q[1];
    }
  }
  __syncthreads();

  const int w   = t >> 6, l = t & 63;
  const int wr  = w >> 1, wc = w & 1;
  const int l15 = l & 15, lq = l >> 4;

  f32x4 acc[4][4];
#pragma unroll
  for (int g = 0; g < 4; ++g)
#pragma unroll
    for (int c = 0; c < 4; ++c) acc[g][c] = (f32x4){0.f, 0.f, 0.f, 0.f};

#pragma unroll
  for (int ks = 0; ks < 4; ++ks) {
    bf16x8 bfr[4];
#pragma unroll
    for (int c = 0; c < 4; ++c)
      bfr[c] = *(const bf16x8*)(wb +
                (size_t)(((ks * 8 + wc * 4 + c) * 64 + l) * 8));
    bf16x8 afr[4];
#pragma unroll
    for (int g = 0; g < 4; ++g) {
      const int row = wr * 64 + g * 16 + l15;   // row & 15 == l15
      const int s   = (ks * 4 + lq) ^ l15;
      afr[g] = *(const bf16x8*)&a_lds[row * 128 + s * 8];
    }
#pragma unroll
    for (int g = 0; g < 4; ++g)
#pragma unroll
      for (int c = 0; c < 4; ++c)
        acc[g][c] = __builtin_amdgcn_mfma_f32_16x16x32_bf16(
            afr[g], bfr[c], acc[g][c], 0, 0, 0);
  }

  // epilogue: + msg + bias, with per-column sum/sumsq accumulation
  float csum[4] = {0.f, 0.f, 0.f, 0.f}, csq[4] = {0.f, 0.f, 0.f, 0.f};
#pragma unroll
  for (int g = 0; g < 4; ++g) {
#pragma unroll
    for (int c = 0; c < 4; ++c) {
      const int col = wc * 64 + c * 16 + l15;
      const float bbl = bl[col];
#pragma unroll
      for (int r = 0; r < 4; ++r) {
        const int grow = row0 + wr * 64 + g * 16 + lq * 4 + r;
        if (grow < N_CELL) {
          const float val =
              acc[g][c][r] + msg[(size_t)grow * DIM + col] + bbl;
          out[(size_t)grow * DIM + col] = val;
          csum[c] += val;
          csq[c]  += val * val;
        }
      }
    }
  }
#pragma unroll
  for (int c = 0; c < 4; ++c) {
    csum[c] += __shfl_xor(csum[c], 16);
    csum[c] += __shfl_xor(csum[c], 32);
    csq[c]  += __shfl_xor(csq[c], 16);
    csq[c]  += __shfl_xor(csq[c], 32);
  }
  if (lq == 0) {
#pragma unroll
    for (int c = 0; c < 4; ++c) {
      ps[w][c * 16 + l15]  = csum[c];
      ps2[w][c * 16 + l15] = csq[c];
    }
  }
  __syncthreads();
  {
    const int which = t >> 7;          // 0: sum, 1: sumsq
    const int col   = t & 127;
    const int wcc   = col >> 6;        // waves wcc and 2+wcc share this col
    const int idx   = col & 63;
    const float v = which ? (ps2[wcc][idx] + ps2[2 + wcc][idx])
                          : (ps[wcc][idx] + ps[2 + wcc][idx]);
    unsafeAtomicAdd(&stats[t], v);     // t in [0,256): sum[128] | sumsq[128]
  }
}

// ---------------------------------------------------------------------------
// bn_finalize: mu / inv_std from accumulated sums (1 block, ~2 us)
// ---------------------------------------------------------------------------
__global__ __launch_bounds__(128) void bn_finalize(float* __restrict__ stats) {
  const int j = threadIdx.x;
  const float mu  = stats[j] / (float)N_CELL;
  const float var = stats[128 + j] / (float)N_CELL - mu * mu;
  stats[256 + j] = mu;
  stats[384 + j] = rsqrtf(var + EPS_BN);
}

// ---------------------------------------------------------------------------
// bn_apply: normalize in place (float4)
// ---------------------------------------------------------------------------
__global__ __launch_bounds__(256) void bn_apply(
    float* __restrict__ out, const float* __restrict__ stats) {
  const size_t total = (size_t)N_CELL * DIM / 4;
  const size_t step  = (size_t)gridDim.x * blockDim.x;
  for (size_t i = (size_t)blockIdx.x * blockDim.x + threadIdx.x; i < total;
       i += step) {
    float4 v = ((float4*)out)[i];
    const int col = (int)((i * 4) & (DIM - 1));
    v.x = (v.x - stats[256 + col + 0]) * stats[384 + col + 0];
    v.y = (v.y - stats[256 + col + 1]) * stats[384 + col + 1];
    v.z = (v.z - stats[256 + col + 2]) * stats[384 + col + 2];
    v.w = (v.w - stats[256 + col + 3]) * stats[384 + col + 3];
    ((float4*)out)[i] = v;
  }
}

// ---------------------------------------------------------------------------
extern "C" void kernel_launch(void* const* d_in, const int* in_sizes, int n_in,
                              void* d_out, int out_size, void* d_ws,
                              size_t ws_size, hipStream_t stream) {
  const float* x_cell = (const float*)d_in[0];
  const float* x_gene = (const float*)d_in[1];
  const float* Wl_gc  = (const float*)d_in[2];
  const float* bl_gc  = (const float*)d_in[3];
  const float* Wr_gc  = (const float*)d_in[4];
  // d_in[5..7] (cg weights) are dead: the gene branch never feeds the output.
  const int* gc_src = (const int*)d_in[8];
  const int* gc_dst = (const int*)d_in[9];
  const int  E      = in_sizes[8];

  const float* Wl1 = Wl_gc + DIM * DIM;   // layer 1 (last)
  const float* bl1 = bl_gc + DIM;
  const float* Wr1 = Wr_gc + DIM * DIM;

  float* ws    = (float*)d_ws;
  float* stats = ws + WS_STATS;
  int*   gcur  = (int*)(ws + WS_GCUR);
  float* msg   = ws + WS_MSG;
  unsigned short* ygene  = (unsigned short*)(ws + WS_YGENE);
  unsigned int*   gedges = (unsigned int*)(ws + WS_GEDGE);
  unsigned short* Wb     = (unsigned short*)(ws + WS_WB);
  float* out   = (float*)d_out;

  // zero stats + bucket counters (4 KB)
  hipMemsetAsync(d_ws, 0, (size_t)WS_ZERO * sizeof(float), stream);

  conv_w<<<64, 256, 0, stream>>>(Wr1, Wb);
  ygene_gemm<<<N_GENE / 8, 128, 0, stream>>>(x_gene, Wl1, ygene);

  const int npart = (E / 4 + PBLK_I4 - 1) / PBLK_I4;   // 184 blocks
  partition_edges<<<npart, 256, 0, stream>>>(gc_src, gc_dst, gcur, gedges, E);
  bucket_aggregate<<<NBUCKET * 4, 256, 0, stream>>>(gedges, gcur, ygene, msg);

  main_gemm_mfma<<<NB_GEMM, 256, 0, stream>>>(x_cell, Wb, bl1, msg, out,
                                              stats);

  bn_finalize<<<1, 128, 0, stream>>>(stats);
  bn_apply<<<2048, 256, 0, stream>>>(out, stats);
}

// Round 11
// 123.881 us; speedup vs baseline: 2.8923x; 1.0086x over previous
//
#include <hip/hip_runtime.h>

// Problem constants (from reference)
#define N_CELL 60000
#define N_GENE 4000
#define DIM    128
#define EPS_BN 1e-5f

#define NBUCKET 469            // ceil(60000/128) buckets of 128 cells
#define CAP     3700           // per-bucket capacity: mean 3200, +8.8 sigma
#define CAP_Q   1024           // per-quarter capacity: mean 800, +8 sigma
#define PBLK_I4 2048           // int4s per partition block (= 8192 edges)
#define NB_GEMM ((N_CELL + 63) / 64)     // 938 main-GEMM blocks (R11: 64-row tiles)

// Workspace layout (4-byte words).  Zeroed region = first WS_ZERO words.
//   stats  [512]             @ 0        (sum,sumsq,mu,istd — 128 each)
//   gcur   [512]             @ 512      (int; per-bucket edge counters)
//   --- end of zeroed region (1024 words) ---
//   msgb   [N_CELL*DIM bf16] @ 1024      (3.84M w) -> ends 3,841,024
//   preb   [N_CELL*DIM bf16] @ 3,841,024 (3.84M w) -> ends 7,681,024
//   ygene  [N_GENE*DIM bf16] @ 7,681,024 (256K w)  -> ends 7,937,024
//   gedges [NBUCKET*CAP u32] @ 8,193,024           -> ends 9,928,324
//   Wb     [16384 bf16]      @ 9,928,324 (8192 w)  -> ends 9,936,516
// total 9,936,516 words = 39.75 MB
#define WS_STATS  0
#define WS_GCUR   512
#define WS_ZERO   1024
#define WS_MSGB   1024
#define WS_PREB   3841024
#define WS_YGENE  7681024
#define WS_GEDGE  8193024
#define WS_WB     9928324

typedef __bf16 bf16x8 __attribute__((ext_vector_type(8)));
typedef float  f32x4  __attribute__((ext_vector_type(4)));

__device__ __forceinline__ float bflo(unsigned int u) {
  return __uint_as_float(u << 16);
}
__device__ __forceinline__ float bfhi(unsigned int u) {
  return __uint_as_float(u & 0xFFFF0000u);
}
__device__ __forceinline__ float bf2f(unsigned short u) {
  return __uint_as_float((unsigned int)u << 16);
}
__device__ __forceinline__ unsigned short f2bf(float f) {
  const __bf16 b = (__bf16)f;
  return __builtin_bit_cast(unsigned short, b);
}

// ---------------------------------------------------------------------------
// Kernel 1: y_gene = bf16(x_gene @ Wl)  — fp32 accumulate, bf16 store.
// ---------------------------------------------------------------------------
__global__ __launch_bounds__(128) void ygene_gemm(
    const float* __restrict__ xg, const float* __restrict__ Wl,
    unsigned short* __restrict__ y) {
  const int j  = threadIdx.x;
  const int r0 = blockIdx.x * 8;
  float acc[8] = {};
  for (int k = 0; k < DIM; ++k) {
    const float w = Wl[k * DIM + j];
#pragma unroll
    for (int r = 0; r < 8; ++r)
      acc[r] += xg[(size_t)(r0 + r) * DIM + k] * w;
  }
#pragma unroll
  for (int r = 0; r < 8; ++r)
    y[(size_t)(r0 + r) * DIM + j] = f2bf(acc[r]);
}

// ---------------------------------------------------------------------------
// conv_w: Wr fp32 [128k][128j] -> fragment-ordered bf16 for 16x16x32 MFMA.
// ---------------------------------------------------------------------------
__global__ __launch_bounds__(256) void conv_w(
    const float* __restrict__ w, unsigned short* __restrict__ wb) {
  const int i = blockIdx.x * 256 + threadIdx.x;  // 0..16383
  const int k = i >> 7, j = i & 127;
  const int chunk = (k >> 5) * 8 + (j >> 4);
  const int lane  = ((k >> 3) & 3) * 16 + (j & 15);
  const int e     = k & 7;
  wb[(chunk * 64 + lane) * 8 + e] = f2bf(w[i]);
}

// ---------------------------------------------------------------------------
// partition_edges: pack (dst<<12 | src) and counting-sort 8192-edge chunks
// into 469 global bucket regions (bucket = dst>>7).  LDS-local sort makes
// the global writes contiguous runs instead of random 4 B scatters.
// hist/off/cur/gbase sized 512 and FULLY zeroed (scan reads 0..511).
// ---------------------------------------------------------------------------
__global__ __launch_bounds__(256) void partition_edges(
    const int* __restrict__ src, const int* __restrict__ dst,
    int* __restrict__ gcur, unsigned int* __restrict__ gedges, int E) {
  __shared__ unsigned int sorted[PBLK_I4 * 4];  // 32 KB
  __shared__ int hist[512], off[512];
  __shared__ int cur[512], gbase[512];
  __shared__ int sc[256];
  __shared__ int tot;
  const int t = threadIdx.x;

  hist[t] = 0;
  hist[256 + t] = 0;
  __syncthreads();

  // ---- load 32 edges/thread into registers, pack, histogram ----
  const int n4    = E >> 2;                 // E divisible by 4 (1.5e6)
  const int base4 = blockIdx.x * PBLK_I4;
  unsigned int pk[32];
#pragma unroll
  for (int k = 0; k < 8; ++k) {
    const int i4 = base4 + k * 256 + t;
    if (i4 < n4) {
      const int4 d4 = ((const int4*)dst)[i4];
      const int4 s4 = ((const int4*)src)[i4];
      pk[k * 4 + 0] = ((unsigned)d4.x << 12) | (unsigned)s4.x;
      pk[k * 4 + 1] = ((unsigned)d4.y << 12) | (unsigned)s4.y;
      pk[k * 4 + 2] = ((unsigned)d4.z << 12) | (unsigned)s4.z;
      pk[k * 4 + 3] = ((unsigned)d4.w << 12) | (unsigned)s4.w;
#pragma unroll
      for (int j = 0; j < 4; ++j)
        atomicAdd(&hist[pk[k * 4 + j] >> 19], 1);
    } else {
#pragma unroll
      for (int j = 0; j < 4; ++j) pk[k * 4 + j] = 0xFFFFFFFFu;
    }
  }
  __syncthreads();

  // ---- exclusive scan of hist[0..511]: pair-sum + Hillis-Steele(256) ----
  const int h0 = hist[2 * t];
  const int h1 = hist[2 * t + 1];
  const int pairsum = h0 + h1;
  sc[t] = pairsum;
  __syncthreads();
#pragma unroll
  for (int o = 1; o < 256; o <<= 1) {
    const int v = (t >= o) ? sc[t - o] : 0;
    __syncthreads();
    sc[t] += v;
    __syncthreads();
  }
  {
    const int excl = sc[t] - pairsum;       // exclusive over pairs
    off[2 * t]     = excl;
    off[2 * t + 1] = excl + h0;
    if (t == 255) tot = sc[255];
  }
  __syncthreads();

  // ---- reserve global ranges, zero local cursors ----
  cur[t] = 0;
  cur[256 + t] = 0;
  for (int i = t; i < 512; i += 256)
    gbase[i] = (i < NBUCKET && hist[i] > 0) ? atomicAdd(&gcur[i], hist[i]) : 0;
  __syncthreads();

  // ---- local scatter: registers -> bucket-sorted LDS ----
#pragma unroll
  for (int k = 0; k < 32; ++k) {
    const unsigned int p = pk[k];
    if (p != 0xFFFFFFFFu) {
      const int b   = p >> 19;
      const int pos = atomicAdd(&cur[b], 1);
      sorted[off[b] + pos] = p;
    }
  }
  __syncthreads();

  // ---- coalesced-run write-out ----
  for (int j = t; j < tot; j += 256) {
    const unsigned int p = sorted[j];
    const int b   = p >> 19;
    const int idx = gbase[b] + (j - off[b]);
    if (idx < CAP) gedges[(size_t)b * CAP + idx] = p;
  }
}

// ---------------------------------------------------------------------------
// bucket_aggregate: 4 blocks per bucket (32-cell quarters).  bf16 gather
// from L2-resident y_gene; R11: msg written as bf16 (halves write traffic).
// ---------------------------------------------------------------------------
__global__ __launch_bounds__(256) void bucket_aggregate(
    const unsigned int* __restrict__ gedges, const int* __restrict__ gcur,
    const unsigned short* __restrict__ yb, unsigned short* __restrict__ msgb) {
  __shared__ unsigned short srt[CAP_Q];        // 2 KB: src per edge, cell-sorted
  __shared__ int counts[32], coff[32], ccur[32];
  __shared__ int sc[32];
  const int b = blockIdx.x >> 2;               // bucket
  const int q = blockIdx.x & 3;                // quarter (32 cells)
  const int t = threadIdx.x;

  int cnt = gcur[b];
  if (cnt > CAP) cnt = CAP;

  if (t < 32) { counts[t] = 0; ccur[t] = 0; }
  __syncthreads();

  // ---- stage bucket edges, keep only our quarter, histogram ----
  unsigned int e[15];                          // 15*256 = 3840 >= CAP
#pragma unroll
  for (int k = 0; k < 15; ++k) {
    const int j = k * 256 + t;
    unsigned int v = (j < cnt) ? gedges[(size_t)b * CAP + j] : 0xFFFFFFFFu;
    // cell = (v>>12)&127; quarter = cell>>5 = (v>>17)&3
    if (v != 0xFFFFFFFFu && (int)((v >> 17) & 3) == q) {
      e[k] = v;
      atomicAdd(&counts[(v >> 12) & 31], 1);
    } else {
      e[k] = 0xFFFFFFFFu;
    }
  }
  __syncthreads();

  // ---- exclusive scan of counts[32] ----
  if (t < 32) sc[t] = counts[t];
  __syncthreads();
#pragma unroll
  for (int o = 1; o < 32; o <<= 1) {
    int v = 0;
    if (t < 32 && t >= o) v = sc[t - o];
    __syncthreads();
    if (t < 32) sc[t] += v;
    __syncthreads();
  }
  if (t < 32) coff[t] = sc[t] - counts[t];
  __syncthreads();

  // ---- scatter src indices into cell-sorted LDS (u16) ----
#pragma unroll
  for (int k = 0; k < 15; ++k) {
    if (e[k] != 0xFFFFFFFFu) {
      const int c   = (e[k] >> 12) & 31;
      const int pos = atomicAdd(&ccur[c], 1);
      const int idx = coff[c] + pos;
      if (idx < CAP_Q) srt[idx] = (unsigned short)(e[k] & 0xFFF);
    }
  }
  __syncthreads();

  // ---- per-cell bf16 gather: wave w owns cells [w*8, w*8+8) ----
  const int w    = t >> 6;
  const int lane = t & 63;
  const int grp  = lane >> 4;                  // edge group 0..3
  const int lsub = lane & 15;                  // 8-dim slice: dims lsub*8..+8
  for (int ci = 0; ci < 8; ++ci) {
    const int c     = w * 8 + ci;                  // cell within quarter
    const int gcell = b * 128 + q * 32 + c;
    if (gcell >= N_CELL) break;                    // wave-uniform
    const int beg = coff[c], num = counts[c];

    float a0[8] = {}, a1[8] = {};
    int ei = grp;
    for (; ei + 4 < num; ei += 8) {                // 2-deep, 4 groups
      const int s0 = srt[beg + ei];
      const int s1 = srt[beg + ei + 4];
      const uint4 v0 = *(const uint4*)(yb + (size_t)s0 * DIM + lsub * 8);
      const uint4 v1 = *(const uint4*)(yb + (size_t)s1 * DIM + lsub * 8);
      a0[0] += bflo(v0.x); a0[1] += bfhi(v0.x);
      a0[2] += bflo(v0.y); a0[3] += bfhi(v0.y);
      a0[4] += bflo(v0.z); a0[5] += bfhi(v0.z);
      a0[6] += bflo(v0.w); a0[7] += bfhi(v0.w);
      a1[0] += bflo(v1.x); a1[1] += bfhi(v1.x);
      a1[2] += bflo(v1.y); a1[3] += bfhi(v1.y);
      a1[4] += bflo(v1.z); a1[5] += bfhi(v1.z);
      a1[6] += bflo(v1.w); a1[7] += bfhi(v1.w);
    }
    if (ei < num) {                                // tail edge for this group
      const int s = srt[beg + ei];
      const uint4 v = *(const uint4*)(yb + (size_t)s * DIM + lsub * 8);
      a0[0] += bflo(v.x); a0[1] += bfhi(v.x);
      a0[2] += bflo(v.y); a0[3] += bfhi(v.y);
      a0[4] += bflo(v.z); a0[5] += bfhi(v.z);
      a0[6] += bflo(v.w); a0[7] += bfhi(v.w);
    }
    // combine the 4 edge-groups (lanes xor 16, xor 32 share lsub)
    float r[8];
#pragma unroll
    for (int d = 0; d < 8; ++d) {
      float s = a0[d] + a1[d];
      s += __shfl_xor(s, 16);
      s += __shfl_xor(s, 32);
      r[d] = s;
    }
    if (grp == 0) {
      const float ic = 1.0f / fmaxf((float)num, 1.0f);
      const unsigned int o0 =
          ((unsigned int)f2bf(r[1] * ic) << 16) | f2bf(r[0] * ic);
      const unsigned int o1 =
          ((unsigned int)f2bf(r[3] * ic) << 16) | f2bf(r[2] * ic);
      const unsigned int o2 =
          ((unsigned int)f2bf(r[5] * ic) << 16) | f2bf(r[4] * ic);
      const unsigned int o3 =
          ((unsigned int)f2bf(r[7] * ic) << 16) | f2bf(r[6] * ic);
      *(uint4*)(msgb + (size_t)gcell * DIM + lsub * 8) =
          make_uint4(o0, o1, o2, o3);
    }
  }
}

// ---------------------------------------------------------------------------
// main GEMM on matrix cores, R11: 64-row tiles (938 blocks; R10's 469-block
// 128-tile was latency-bound at 15% occupancy).  Wave w owns cols
// [w*32, w*32+32) x all 64 rows.  pre written bf16 to ws; BN stats in fp32,
// one atomicAdd per thread into stats[0:256].
// ---------------------------------------------------------------------------
__global__ __launch_bounds__(256) void main_gemm_mfma(
    const float* __restrict__ xc, const unsigned short* __restrict__ wb,
    const float* __restrict__ bl, const unsigned short* __restrict__ msgb,
    unsigned short* __restrict__ preb, float* __restrict__ stats) {
  __shared__ unsigned short a_lds[64 * 128];   // 16 KB
  __shared__ float ps[4][32], ps2[4][32];      // per-wave BN partials
  const int t    = threadIdx.x;
  const int row0 = blockIdx.x * 64;

  // ---- stage A: fp32 -> bf16, swizzled; thread t: row t>>2, K-quarter t&3
  {
    const int row  = t >> 2;
    const int h    = t & 3;
    const int grow = row0 + row;
    const bool ok  = grow < N_CELL;
    const float* xrow = xc + (size_t)grow * DIM;
#pragma unroll
    for (int i = 0; i < 2; ++i) {
      const int kk = h * 32 + i * 16;
      float4 f0, f1, f2, f3;
      if (ok) {
        f0 = *(const float4*)(xrow + kk);
        f1 = *(const float4*)(xrow + kk + 4);
        f2 = *(const float4*)(xrow + kk + 8);
        f3 = *(const float4*)(xrow + kk + 12);
      } else {
        f0 = f1 = f2 = f3 = make_float4(0.f, 0.f, 0.f, 0.f);
      }
      const float fv[16] = {f0.x, f0.y, f0.z, f0.w, f1.x, f1.y, f1.z, f1.w,
                            f2.x, f2.y, f2.z, f2.w, f3.x, f3.y, f3.z, f3.w};
      union { unsigned short u[16]; uint4 q[2]; } pk;
#pragma unroll
      for (int e = 0; e < 16; ++e) pk.u[e] = f2bf(fv[e]);
      const int s0 = ((kk >> 3) + 0) ^ (row & 15);
      const int s1 = ((kk >> 3) + 1) ^ (row & 15);
      *(uint4*)&a_lds[row * 128 + s0 * 8] = pk.q[0];
      *(uint4*)&a_lds[row * 128 + s1 * 8] = pk.q[1];
    }
  }
  __syncthreads();

  const int w   = t >> 6, l = t & 63;
  const int l15 = l & 15, lq = l >> 4;

  f32x4 acc[4][2];
#pragma unroll
  for (int g = 0; g < 4; ++g)
#pragma unroll
    for (int c = 0; c < 2; ++c) acc[g][c] = (f32x4){0.f, 0.f, 0.f, 0.f};

#pragma unroll
  for (int ks = 0; ks < 4; ++ks) {
    bf16x8 bfr[2];
#pragma unroll
    for (int c = 0; c < 2; ++c) {
      const int cf = w * 2 + c;                 // col fragment 0..7
      bfr[c] = *(const bf16x8*)(wb +
                (size_t)(((ks * 8 + cf) * 64 + l) * 8));
    }
    bf16x8 afr[4];
#pragma unroll
    for (int g = 0; g < 4; ++g) {
      const int row = g * 16 + l15;             // row & 15 == l15
      const int s   = (ks * 4 + lq) ^ l15;
      afr[g] = *(const bf16x8*)&a_lds[row * 128 + s * 8];
    }
#pragma unroll
    for (int g = 0; g < 4; ++g)
#pragma unroll
      for (int c = 0; c < 2; ++c)
        acc[g][c] = __builtin_amdgcn_mfma_f32_16x16x32_bf16(
            afr[g], bfr[c], acc[g][c], 0, 0, 0);
  }

  // epilogue: + msg(bf16) + bias -> pre(bf16), BN sum/sumsq in fp32
  float csum[2] = {0.f, 0.f}, csq[2] = {0.f, 0.f};
#pragma unroll
  for (int g = 0; g < 4; ++g) {
#pragma unroll
    for (int c = 0; c < 2; ++c) {
      const int col = (w * 2 + c) * 16 + l15;
      const float bbl = bl[col];
#pragma unroll
      for (int r = 0; r < 4; ++r) {
        const int grow = row0 + g * 16 + lq * 4 + r;
        if (grow < N_CELL) {
          const float val =
              acc[g][c][r] + bf2f(msgb[(size_t)grow * DIM + col]) + bbl;
          preb[(size_t)grow * DIM + col] = f2bf(val);
          csum[c] += val;
          csq[c]  += val * val;
        }
      }
    }
  }
  // reduce the 4 lanes (lq=0..3) that share each column
#pragma unroll
  for (int c = 0; c < 2; ++c) {
    csum[c] += __shfl_xor(csum[c], 16);
    csum[c] += __shfl_xor(csum[c], 32);
    csq[c]  += __shfl_xor(csq[c], 16);
    csq[c]  += __shfl_xor(csq[c], 32);
  }
  if (lq == 0) {
#pragma unroll
    for (int c = 0; c < 2; ++c) {
      ps[w][c * 16 + l15]  = csum[c];   // col = w*32 + c*16 + l15
      ps2[w][c * 16 + l15] = csq[c];
    }
  }
  __syncthreads();
  {
    const int which = t >> 7;          // 0: sum, 1: sumsq
    const int col   = t & 127;
    const int wi    = col >> 5;        // owning wave
    const int idx   = col & 31;
    const float v = which ? ps2[wi][idx] : ps[wi][idx];
    unsafeAtomicAdd(&stats[t], v);     // t in [0,256): sum[128] | sumsq[128]
  }
}

// ---------------------------------------------------------------------------
// bn_finalize: mu / inv_std from accumulated sums (1 block, ~2 us)
// ---------------------------------------------------------------------------
__global__ __launch_bounds__(128) void bn_finalize(float* __restrict__ stats) {
  const int j = threadIdx.x;
  const float mu  = stats[j] / (float)N_CELL;
  const float var = stats[128 + j] / (float)N_CELL - mu * mu;
  stats[256 + j] = mu;
  stats[384 + j] = rsqrtf(var + EPS_BN);
}

// ---------------------------------------------------------------------------
// bn_apply: read bf16 pre (L3-hot), write fp32 out
// ---------------------------------------------------------------------------
__global__ __launch_bounds__(256) void bn_apply(
    const unsigned short* __restrict__ preb, float* __restrict__ out,
    const float* __restrict__ stats) {
  const size_t total = (size_t)N_CELL * DIM / 8;
  const size_t step  = (size_t)gridDim.x * blockDim.x;
  for (size_t i = (size_t)blockIdx.x * blockDim.x + threadIdx.x; i < total;
       i += step) {
    const uint4 v = ((const uint4*)preb)[i];
    const int col = (int)((i * 8) & (DIM - 1));
    const float* mu = stats + 256 + col;
    const float* is = stats + 384 + col;
    float4 o0, o1;
    o0.x = (bflo(v.x) - mu[0]) * is[0];
    o0.y = (bfhi(v.x) - mu[1]) * is[1];
    o0.z = (bflo(v.y) - mu[2]) * is[2];
    o0.w = (bfhi(v.y) - mu[3]) * is[3];
    o1.x = (bflo(v.z) - mu[4]) * is[4];
    o1.y = (bfhi(v.z) - mu[5]) * is[5];
    o1.z = (bflo(v.w) - mu[6]) * is[6];
    o1.w = (bfhi(v.w) - mu[7]) * is[7];
    *(float4*)(out + i * 8)     = o0;
    *(float4*)(out + i * 8 + 4) = o1;
  }
}

// ---------------------------------------------------------------------------
extern "C" void kernel_launch(void* const* d_in, const int* in_sizes, int n_in,
                              void* d_out, int out_size, void* d_ws,
                              size_t ws_size, hipStream_t stream) {
  const float* x_cell = (const float*)d_in[0];
  const float* x_gene = (const float*)d_in[1];
  const float* Wl_gc  = (const float*)d_in[2];
  const float* bl_gc  = (const float*)d_in[3];
  const float* Wr_gc  = (const float*)d_in[4];
  // d_in[5..7] (cg weights) are dead: the gene branch never feeds the output.
  const int* gc_src = (const int*)d_in[8];
  const int* gc_dst = (const int*)d_in[9];
  const int  E      = in_sizes[8];

  const float* Wl1 = Wl_gc + DIM * DIM;   // layer 1 (last)
  const float* bl1 = bl_gc + DIM;
  const float* Wr1 = Wr_gc + DIM * DIM;

  float* ws    = (float*)d_ws;
  float* stats = ws + WS_STATS;
  int*   gcur  = (int*)(ws + WS_GCUR);
  unsigned short* msgb   = (unsigned short*)(ws + WS_MSGB);
  unsigned short* preb   = (unsigned short*)(ws + WS_PREB);
  unsigned short* ygene  = (unsigned short*)(ws + WS_YGENE);
  unsigned int*   gedges = (unsigned int*)(ws + WS_GEDGE);
  unsigned short* Wb     = (unsigned short*)(ws + WS_WB);
  float* out   = (float*)d_out;

  // zero stats + bucket counters (4 KB)
  hipMemsetAsync(d_ws, 0, (size_t)WS_ZERO * sizeof(float), stream);

  conv_w<<<64, 256, 0, stream>>>(Wr1, Wb);
  ygene_gemm<<<N_GENE / 8, 128, 0, stream>>>(x_gene, Wl1, ygene);

  const int npart = (E / 4 + PBLK_I4 - 1) / PBLK_I4;   // 184 blocks
  partition_edges<<<npart, 256, 0, stream>>>(gc_src, gc_dst, gcur, gedges, E);
  bucket_aggregate<<<NBUCKET * 4, 256, 0, stream>>>(gedges, gcur, ygene, msgb);

  main_gemm_mfma<<<NB_GEMM, 256, 0, stream>>>(x_cell, Wb, bl1, msgb, preb,
                                              stats);

  bn_finalize<<<1, 128, 0, stream>>>(stats);
  bn_apply<<<2048, 256, 0, stream>>>(preb, out, stats);
}